// Round 17
// baseline (269.247 us; speedup 1.0000x reference)
//
#include <hip/hip_runtime.h>

typedef unsigned short u16;
typedef unsigned int u32;

#define B_ 4
#define S_ 4
#define NTOK 1029
#define CDIM 2048
#define PSI 5
#define NPB 4096
#define MROWS 16384
#define N1 1024
#define N2 256
#define MD 64
#define MA 65

using bf16x8 = __attribute__((ext_vector_type(8))) short;
using f32x4  = __attribute__((ext_vector_type(4))) float;
using u16x8  = __attribute__((ext_vector_type(8))) unsigned short;

typedef __attribute__((address_space(1))) const void global_cvoid;
typedef __attribute__((address_space(3))) void lds_void;

__device__ __forceinline__ u16 f2b(float f) {
  u32 u = __builtin_bit_cast(u32, f);
  u32 r = (u + 0x7fffu + ((u >> 16) & 1u)) >> 16;
  return (u16)r;
}

// ---------------- merged prep: patch convert (fp32->bf16) + W1t/W2t/bias packs -------
__global__ void k_prep_patch(const float* __restrict__ tokens, u16* __restrict__ Abf,
                             const float* __restrict__ pfw1, const float* __restrict__ psw1,
                             const float* __restrict__ pfw2, const float* __restrict__ psw2,
                             const float* __restrict__ pfb1, const float* __restrict__ psb1,
                             const float* __restrict__ pfb2, const float* __restrict__ psb2,
                             u16* __restrict__ W1t, u16* __restrict__ W2t,
                             float* __restrict__ b1c, float* __restrict__ b2c) {
  __shared__ float tile[32][33];
  int id = blockIdx.x, tid = threadIdx.x;
  if (id < 16384) {
    size_t idx = (size_t)id * 256 + tid;
    size_t r = idx >> 8;
    int cv = (int)(idx & 255) << 3;
    int b = (int)(r >> 12), s = (int)((r >> 10) & 3), j = (int)(r & 1023);
    const float* src = tokens + ((size_t)((b * S_ + s) * NTOK + PSI + j)) * CDIM + cv;
    float4 v0 = *(const float4*)src;
    float4 v1 = *(const float4*)(src + 4);
    u16x8 o;
    o[0] = f2b(v0.x); o[1] = f2b(v0.y); o[2] = f2b(v0.z); o[3] = f2b(v0.w);
    o[4] = f2b(v1.x); o[5] = f2b(v1.y); o[6] = f2b(v1.z); o[7] = f2b(v1.w);
    *(u16x8*)(Abf + r * CDIM + cv) = o;
    return;
  }
  int id2 = id - 16384;
  int tx = tid & 31, ty = tid >> 5;
  if (id2 < 2048) {
    int kb = (id2 & 63) * 32, nb = (id2 >> 6) * 32;
    #pragma unroll
    for (int i = 0; i < 4; ++i) {
      int k = kb + ty + i * 8, n = nb + tx;
      tile[ty + i * 8][tx] = (n < 512) ? pfw1[(size_t)k * 512 + n] : psw1[(size_t)k * 512 + (n - 512)];
    }
    __syncthreads();
    #pragma unroll
    for (int i = 0; i < 4; ++i) {
      int n = nb + ty + i * 8, k = kb + tx;
      W1t[(size_t)n * CDIM + k] = f2b(tile[tx][ty + i * 8]);
    }
  } else if (id2 < 2304) {
    int i2 = id2 - 2048;
    int kb = (i2 & 31) * 32, jb = (i2 >> 5) * 32;
    #pragma unroll
    for (int i = 0; i < 4; ++i) {
      int k = kb + ty + i * 8, j = jb + tx;
      float v = 0.f;
      if (j < 128) { if (k < 512) v = pfw2[(size_t)k * 128 + j]; }
      else if (j < 192) { if (k >= 512) v = psw2[(size_t)(k - 512) * 64 + (j - 128)]; }
      tile[ty + i * 8][tx] = v;
    }
    __syncthreads();
    #pragma unroll
    for (int i = 0; i < 4; ++i) {
      int j = jb + ty + i * 8, k = kb + tx;
      W2t[(size_t)j * N1 + k] = f2b(tile[tx][ty + i * 8]);
    }
  } else {
    int t = (id2 - 2304) * 256 + tid;
    if (t < 1024) b1c[t] = (t < 512) ? pfb1[t] : psb1[t - 512];
    if (t < 256)  b2c[t] = (t < 128) ? pfb2[t] : ((t < 192) ? psb2[t - 128] : 0.f);
  }
}

// ---------------- merged cr-side packs: Bt1cr, Bt2cr, Acr ----------------
__global__ void k_pack_cr(const float* __restrict__ camw1, const float* __restrict__ regw1,
                          const float* __restrict__ camw2, const float* __restrict__ regw2,
                          const float* __restrict__ tokens,
                          u16* __restrict__ Bt1cr, u16* __restrict__ Bt2cr,
                          u16* __restrict__ Acr) {
  __shared__ float tile[32][33];
  int id = blockIdx.x, tid = threadIdx.x;
  int tx = tid & 31, ty = tid >> 5;
  if (id < 4096) {
    const float* src = (id < 2048) ? camw1 : regw1;
    u16* dst = Bt1cr + ((id < 2048) ? 0 : (size_t)1024 * CDIM);
    int i2 = id & 2047;
    int kb = (i2 & 63) * 32, nb = (i2 >> 6) * 32;
    #pragma unroll
    for (int i = 0; i < 4; ++i)
      tile[ty + i * 8][tx] = src[(size_t)(kb + ty + i * 8) * 1024 + nb + tx];
    __syncthreads();
    #pragma unroll
    for (int i = 0; i < 4; ++i)
      dst[(size_t)(nb + ty + i * 8) * CDIM + kb + tx] = f2b(tile[tx][ty + i * 8]);
  } else if (id < 5120) {
    int i3 = id - 4096;
    const float* src = (i3 < 512) ? camw2 : regw2;
    u16* dst = Bt2cr + ((i3 < 512) ? 0 : (size_t)512 * N1);
    int i2 = i3 & 511;
    int kb = (i2 & 31) * 32, nb = (i2 >> 5) * 32;
    #pragma unroll
    for (int i = 0; i < 4; ++i)
      tile[ty + i * 8][tx] = src[(size_t)(kb + ty + i * 8) * 512 + nb + tx];
    __syncthreads();
    #pragma unroll
    for (int i = 0; i < 4; ++i)
      dst[(size_t)(nb + ty + i * 8) * N1 + kb + tx] = f2b(tile[tx][ty + i * 8]);
  } else {
    int r = id - 5120;
    int c0 = tid << 3;
    u16x8 o;
    if (r >= 80) {
      #pragma unroll
      for (int i = 0; i < 8; ++i) o[i] = 0;
    } else {
      const float* src;
      if (r < 16) { int b = r >> 2, s = r & 3; src = tokens + ((size_t)(b * S_ + s) * NTOK) * CDIM; }
      else { int r2 = r - 16; int b = r2 >> 4, q = r2 & 15, s = q >> 2, t = (q & 3) + 1;
             src = tokens + ((size_t)(b * S_ + s) * NTOK + t) * CDIM; }
      float4 v0 = *(const float4*)(src + c0);
      float4 v1 = *(const float4*)(src + c0 + 4);
      o[0] = f2b(v0.x); o[1] = f2b(v0.y); o[2] = f2b(v0.z); o[3] = f2b(v0.w);
      o[4] = f2b(v1.x); o[5] = f2b(v1.y); o[6] = f2b(v1.z); o[7] = f2b(v1.w);
    }
    *(u16x8*)(Acr + (size_t)r * CDIM + c0) = o;
  }
}

// ---------------- bf16 MFMA GEMM: 2-buf, counted vmcnt(8), raw barriers, T2 swizzle --
#define STAGE_TILE(buf, k0)                                                    \
  {                                                                            \
    _Pragma("unroll")                                                          \
    for (int r = 0; r < 4; ++r) {                                              \
      __builtin_amdgcn_global_load_lds(                                        \
          (global_cvoid*)(A + abase + (size_t)(r * 32) * K + (k0)),            \
          (lds_void*)(&As[buf][lofs + r * 2048]), 16, 0, 0);                   \
      __builtin_amdgcn_global_load_lds(                                        \
          (global_cvoid*)(Bt + bbase + (size_t)(r * 32) * K + (k0)),           \
          (lds_void*)(&Bs[buf][lofs + r * 2048]), 16, 0, 0);                   \
    }                                                                          \
  }

#define COMPUTE_TILE(buf)                                                      \
  {                                                                            \
    _Pragma("unroll")                                                          \
    for (int kk = 0; kk < 64; kk += 32) {                                      \
      const int csw = (kk + hi8) ^ ((lane & 7) << 3);                          \
      bf16x8 af[4], bfr[4];                                                    \
      _Pragma("unroll")                                                        \
      for (int i = 0; i < 4; ++i) {                                            \
        af[i]  = *(const bf16x8*)&As[buf][((wr << 6) + (i << 4) + (lane & 15)) * 64 + csw]; \
        bfr[i] = *(const bf16x8*)&Bs[buf][((wc << 6) + (i << 4) + (lane & 15)) * 64 + csw]; \
      }                                                                        \
      _Pragma("unroll")                                                        \
      for (int mi = 0; mi < 4; ++mi)                                           \
        _Pragma("unroll")                                                      \
        for (int ni = 0; ni < 4; ++ni)                                         \
          acc[mi][ni] = __builtin_amdgcn_mfma_f32_16x16x32_bf16(af[mi], bfr[ni], acc[mi][ni], 0, 0, 0); \
    }                                                                          \
  }

template <int RELU, int OUTBF, int WRSC>
__global__ __launch_bounds__(256, 2)
void k_gemm(const u16* __restrict__ A, const u16* __restrict__ Bt,
            const float* __restrict__ bias, void* __restrict__ Cout,
            int M, int N, int K, float* __restrict__ ScOut) {
  __shared__ u16 As[2][128 * 64];
  __shared__ u16 Bs[2][128 * 64];
  const int tid = threadIdx.x;
  const int lane = tid & 63;
  const int wave = tid >> 6;
  const int tM = blockIdx.x << 7;
  const int tN = blockIdx.y << 7;
  const int wr = wave >> 1, wc = wave & 1;
  const int hi8 = (lane >> 4) << 3;

  const int srow = (wave << 3) + (lane >> 3);
  const int scolsw = ((lane & 7) ^ (lane >> 3)) << 3;
  const size_t abase = (size_t)(tM + srow) * K + scolsw;
  const size_t bbase = (size_t)(tN + srow) * K + scolsw;
  const int lofs = (wave << 9) + (lane << 3);

  f32x4 acc[4][4];
  #pragma unroll
  for (int i = 0; i < 4; ++i)
    #pragma unroll
    for (int j = 0; j < 4; ++j)
      acc[i][j] = (f32x4){0.f, 0.f, 0.f, 0.f};

  const int nt = K >> 6;
  STAGE_TILE(0, 0)
  STAGE_TILE(1, 64)
  for (int t = 0; t < nt; t += 2) {
    asm volatile("s_waitcnt vmcnt(8)" ::: "memory");
    __builtin_amdgcn_s_barrier();
    COMPUTE_TILE(0)
    __builtin_amdgcn_s_barrier();
    if (t + 2 < nt) STAGE_TILE(0, (t + 2) << 6)
    if (t + 1 == nt - 1) {
      asm volatile("s_waitcnt vmcnt(0)" ::: "memory");
    } else {
      asm volatile("s_waitcnt vmcnt(8)" ::: "memory");
    }
    __builtin_amdgcn_s_barrier();
    COMPUTE_TILE(1)
    __builtin_amdgcn_s_barrier();
    if (t + 3 < nt) STAGE_TILE(1, (t + 3) << 6)
  }

  #pragma unroll
  for (int ni = 0; ni < 4; ++ni) {
    const int col = tN + (wc << 6) + (ni << 4) + (lane & 15);
    const float bv = bias[col];
    #pragma unroll
    for (int mi = 0; mi < 4; ++mi) {
      #pragma unroll
      for (int j = 0; j < 4; ++j) {
        const int row = tM + (wr << 6) + (mi << 4) + ((lane >> 4) << 2) + j;
        float vv = acc[mi][ni][j] + bv;
        if (RELU) vv = fmaxf(vv, 0.f);
        if (OUTBF) ((u16*)Cout)[(size_t)row * N + col] = f2b(vv);
        else       ((float*)Cout)[(size_t)row * N + col] = vv;
        if (WRSC) {
          if (col >= 128 && col < 192)
            ScOut[((size_t)((row >> 12) * MD + (col - 128))) * NPB + (row & 4095)] = vv;
        }
      }
    }
  }
}

// ---------------- split-K MFMA GEMM, M=128 fixed (single-buffer, known-good) ----
__global__ __launch_bounds__(256, 2)
void k_gemm_splitk(const u16* __restrict__ A, const u16* __restrict__ Bt,
                   float* __restrict__ part, int N, int K, int KC) {
  __shared__ u16 As1[128 * 64];
  __shared__ u16 Bs1[128 * 64];
  const int tid = threadIdx.x;
  const int lane = tid & 63;
  const int wave = tid >> 6;
  const int tN = blockIdx.y << 7;
  const int kb = blockIdx.z * KC;
  const int wr = wave >> 1, wc = wave & 1;
  const int srow = (wave << 3) + (lane >> 3);
  const int scol = (lane & 7) << 3;
  const size_t abase = (size_t)srow * K + scol;
  const size_t bbase = (size_t)(tN + srow) * K + scol;
  u16* asw = &As1[(wave << 9) + (lane << 3)];
  u16* bsw = &Bs1[(wave << 9) + (lane << 3)];

  f32x4 acc[4][4];
  #pragma unroll
  for (int i = 0; i < 4; ++i)
    #pragma unroll
    for (int j = 0; j < 4; ++j)
      acc[i][j] = (f32x4){0.f, 0.f, 0.f, 0.f};

  for (int k0 = kb; k0 < kb + KC; k0 += 64) {
    #pragma unroll
    for (int r = 0; r < 4; ++r) {
      __builtin_amdgcn_global_load_lds(
          (global_cvoid*)(A + abase + (size_t)(r * 32) * K + k0),
          (lds_void*)(asw + r * 2048), 16, 0, 0);
      __builtin_amdgcn_global_load_lds(
          (global_cvoid*)(Bt + bbase + (size_t)(r * 32) * K + k0),
          (lds_void*)(bsw + r * 2048), 16, 0, 0);
    }
    __syncthreads();
    #pragma unroll
    for (int kk = 0; kk < 64; kk += 32) {
      bf16x8 af[4], bfr[4];
      #pragma unroll
      for (int i = 0; i < 4; ++i) {
        af[i]  = *(const bf16x8*)&As1[((wr << 6) + (i << 4) + (lane & 15)) * 64 + kk + ((lane >> 4) << 3)];
        bfr[i] = *(const bf16x8*)&Bs1[((wc << 6) + (i << 4) + (lane & 15)) * 64 + kk + ((lane >> 4) << 3)];
      }
      #pragma unroll
      for (int mi = 0; mi < 4; ++mi)
        #pragma unroll
        for (int ni = 0; ni < 4; ++ni)
          acc[mi][ni] = __builtin_amdgcn_mfma_f32_16x16x32_bf16(af[mi], bfr[ni], acc[mi][ni], 0, 0, 0);
    }
    __syncthreads();
  }

  float* dst = part + (size_t)blockIdx.z * 128 * N;
  #pragma unroll
  for (int ni = 0; ni < 4; ++ni) {
    const int col = tN + (wc << 6) + (ni << 4) + (lane & 15);
    #pragma unroll
    for (int mi = 0; mi < 4; ++mi) {
      #pragma unroll
      for (int j = 0; j < 4; ++j) {
        const int row = (wr << 6) + (mi << 4) + ((lane >> 4) << 2) + j;
        dst[(size_t)row * N + col] = acc[mi][ni][j];
      }
    }
  }
}

// ---------------- cr fin1: reduce part1(kc=8) + bias + relu -> A2 bf16 [128][1024] ----
__global__ void k_cr_fin1(const float* __restrict__ part1,
                          const float* __restrict__ camb1, const float* __restrict__ regb1,
                          u16* __restrict__ A2) {
  int r = blockIdx.x;
  int j = blockIdx.y * 256 + threadIdx.x;
  if (r >= 80) { A2[(size_t)r * N1 + j] = 0; return; }
  bool cam = (r < 16);
  int cm = j + (cam ? 0 : 1024);
  float s = 0.f;
  #pragma unroll
  for (int kc = 0; kc < 8; ++kc) s += part1[((size_t)kc * 128 + r) * 2048 + cm];
  s += cam ? camb1[j] : regb1[j];
  A2[(size_t)r * N1 + j] = f2b(fmaxf(s, 0.f));
}

// ---------------- cr fin2: reduce part2(kc=8) + bias + l2norm + clip^p -> hp[80][512] -
__global__ __launch_bounds__(512)
void k_cr_fin2(const float* __restrict__ part2,
               const float* __restrict__ camb2, const float* __restrict__ regb2,
               const float* __restrict__ camp, const float* __restrict__ regp,
               float* __restrict__ hp) {
  __shared__ float red[8];
  int r = blockIdx.x;
  int j = threadIdx.x;
  bool cam = (r < 16);
  int cm = j + (cam ? 0 : 512);
  float s = 0.f;
  #pragma unroll
  for (int kc = 0; kc < 8; ++kc) s += part2[((size_t)kc * 128 + r) * 1024 + cm];
  s += cam ? camb2[j] : regb2[j];
  float ss = s * s;
  #pragma unroll
  for (int o = 32; o; o >>= 1) ss += __shfl_down(ss, o);
  if ((j & 63) == 0) red[j >> 6] = ss;
  __syncthreads();
  float tot = 0.f;
  #pragma unroll
  for (int i = 0; i < 8; ++i) tot += red[i];
  float inv = 1.f / fmaxf(sqrtf(tot), 1e-12f);
  float t = fmaxf(s * inv, 1e-6f);
  hp[(size_t)r * 512 + j] = powf(t, cam ? camp[0] : regp[0]);
}

// ---------------- cr3 fused: GeM finalize + L3 + L4 + l2norm, all pb-local ----------
__global__ __launch_bounds__(512)
void k_cr3f(const float* __restrict__ hp,
            const float* __restrict__ camp, const float* __restrict__ camw3,
            const float* __restrict__ camb3, const float* __restrict__ camw4,
            const float* __restrict__ camb4,
            const float* __restrict__ regp, const float* __restrict__ regw3,
            const float* __restrict__ regb3, const float* __restrict__ regw4,
            const float* __restrict__ regb4,
            float* __restrict__ out) {
  __shared__ float gls[512];
  __shared__ float o1s[512];
  __shared__ float partb[4][128];
  __shared__ float partc[2][256];
  __shared__ float vsq[256];
  __shared__ float red[4];
  int pb = blockIdx.x;
  bool cam = (pb < 4);
  int path = pb >> 2, b = pb & 3;
  const float* W3 = cam ? camw3 : regw3;
  const float* B3 = cam ? camb3 : regb3;
  const float* W4 = cam ? camw4 : regw4;
  const float* B4 = cam ? camb4 : regb4;
  float p = cam ? camp[0] : regp[0];
  int L = cam ? 4 : 16;
  int row0 = cam ? b * 4 : 16 + b * 16;
  int tid = threadIdx.x;

  {
    float s = 0.f;
    for (int r = 0; r < L; ++r) s += hp[(size_t)(row0 + r) * 512 + tid];
    gls[tid] = powf(s / (float)L, 1.f / p);
  }
  __syncthreads();

  {
    int col = tid & 127, kq = tid >> 7;
    for (int och = 0; och < 4; ++och) {
      int oc = (och << 7) + col;
      float acc = 0.f;
      const float* w = W3 + (size_t)(kq << 7) * 512 + oc;
      #pragma unroll 8
      for (int kk = 0; kk < 128; ++kk) acc += gls[(kq << 7) + kk] * w[(size_t)kk * 512];
      partb[kq][col] = acc;
      __syncthreads();
      if (kq == 0)
        o1s[oc] = fmaxf(partb[0][col] + partb[1][col] + partb[2][col] + partb[3][col] + B3[oc], 0.f);
      __syncthreads();
    }
  }

  int col = tid & 255, kh = tid >> 8;
  float acc = 0.f;
  {
    const float* w = W4 + (size_t)(kh << 8) * 256 + col;
    #pragma unroll 8
    for (int kk = 0; kk < 256; ++kk) acc += o1s[(kh << 8) + kk] * w[(size_t)kk * 256];
    partc[kh][col] = acc;
  }
  __syncthreads();
  float val = 0.f;
  if (kh == 0) {
    val = partc[0][col] + partc[1][col] + B4[col];
    vsq[col] = val * val;
  }
  __syncthreads();
  float ss = (tid < 256) ? vsq[tid] : 0.f;
  #pragma unroll
  for (int o = 32; o; o >>= 1) ss += __shfl_down(ss, o);
  if (tid < 256 && (tid & 63) == 0) red[tid >> 6] = ss;
  __syncthreads();
  if (kh == 0) {
    float tot = red[0] + red[1] + red[2] + red[3];
    float inv = 1.f / fmaxf(sqrtf(tot), 1e-12f);
    out[(size_t)b * 8704 + 8192 + path * 256 + col] = val * inv;
  }
}

// ---------------- sinkhorn: u update — online LSE; dust row k==64 is virtual ---------
__global__ void k_sink_u(const float* __restrict__ Sc, const float* __restrict__ v,
                         float* __restrict__ u, const float* __restrict__ dust) {
  __shared__ float redm[4], reds[4];
  int b = blockIdx.x / MA, k = blockIdx.x % MA;
  const float* vb = v + (size_t)b * NPB;
  int tid = threadIdx.x;
  float mx = -1e30f, s = 0.f;
  if (k < MD) {
    const float* row = Sc + ((size_t)(b * MD) + k) * NPB;
    for (int n = tid; n < NPB; n += 256) {
      float x = row[n] + vb[n];
      float m2 = fmaxf(mx, x);
      s = s * __expf(mx - m2) + __expf(x - m2);
      mx = m2;
    }
  } else {
    float d0 = dust[0];
    for (int n = tid; n < NPB; n += 256) {
      float x = d0 + vb[n];
      float m2 = fmaxf(mx, x);
      s = s * __expf(mx - m2) + __expf(x - m2);
      mx = m2;
    }
  }
  #pragma unroll
  for (int o = 32; o; o >>= 1) {
    float mo = __shfl_down(mx, o), so = __shfl_down(s, o);
    float m2 = fmaxf(mx, mo);
    s = s * __expf(mx - m2) + so * __expf(mo - m2);
    mx = m2;
  }
  if ((tid & 63) == 0) { redm[tid >> 6] = mx; reds[tid >> 6] = s; }
  __syncthreads();
  if (tid == 0) {
    float M = redm[0];
    #pragma unroll
    for (int i = 1; i < 4; ++i) M = fmaxf(M, redm[i]);
    float S = 0.f;
    #pragma unroll
    for (int i = 0; i < 4; ++i) S += reds[i] * __expf(redm[i] - M);
    const float nrm = -logf((float)(NPB + MD));
    float la = (k == MD) ? (nrm + logf((float)(NPB - MD))) : nrm;
    u[b * MA + k] = la - (M + __logf(S));
  }
}

// ---------------- sinkhorn: v update — one-pass online LSE, 256-thread blocks --------
// (R15 lesson: 64-thread LDS-staged version regressed ~10us — 1 wave/block starves
//  memory-level parallelism; Sc is L2-resident so the extra pass was never the cost.
//  This = R13's proven 64-blk x 256-thr shape with the 2 passes collapsed into 1.)
__global__ __launch_bounds__(256)
void k_sink_v(const float* __restrict__ Sc, const float* __restrict__ u,
              float* __restrict__ v, const float* __restrict__ dust) {
  __shared__ float us[MA];
  int b = blockIdx.x >> 4;
  int n = ((blockIdx.x & 15) << 8) + threadIdx.x;
  if (threadIdx.x < MA) us[threadIdx.x] = u[b * MA + threadIdx.x];
  __syncthreads();
  const float* Sb = Sc + (size_t)b * MD * NPB + n;
  float mx = dust[0] + us[MD], s = 1.f;   // online LSE seeded with the virtual dust term
  #pragma unroll 4
  for (int k = 0; k < MD; ++k) {
    float x = Sb[(size_t)k * NPB] + us[k];
    float m2 = fmaxf(mx, x);
    s = s * __expf(mx - m2) + __expf(x - m2);
    mx = m2;
  }
  const float nrm = -logf((float)(NPB + MD));
  v[(size_t)b * NPB + n] = nrm - (mx + __logf(s));
}

// ---------------- pooled stage 1 (P fused): partial[b][j][c][k] over 64-n chunks ------
__global__ __launch_bounds__(256)
void k_pooled1(const float* __restrict__ FS, const float* __restrict__ Sc,
               const float* __restrict__ u, const float* __restrict__ v,
               float* __restrict__ partial) {
  __shared__ float Fs[64][132];
  __shared__ float Ps[64][68];
  int b = blockIdx.x >> 6, j = blockIdx.x & 63;
  int n0 = j << 6;
  int tid = threadIdx.x;
  {
    int r = tid >> 5;
    int c4 = (tid & 31) << 2;
    #pragma unroll
    for (int i = 0; i < 8; ++i) {
      int n = r + (i << 3);
      float4 vv = *(const float4*)&FS[((size_t)(b * NPB + n0 + n)) * N2 + c4];
      *(float4*)&Fs[n][c4] = vv;
    }
  }
  {
    const float nrm = -logf((float)(NPB + MD));
    int r = tid >> 4;
    int c4 = (tid & 15) << 2;
    #pragma unroll
    for (int i = 0; i < 4; ++i) {
      int k = r + (i << 4);
      float uk = u[b * MA + k];
      float4 sv = *(const float4*)&Sc[((size_t)(b * MD) + k) * NPB + n0 + c4];
      float4 vv = *(const float4*)&v[(size_t)b * NPB + n0 + c4];
      float4 o;
      o.x = __expf(sv.x + uk + vv.x - nrm);
      o.y = __expf(sv.y + uk + vv.y - nrm);
      o.z = __expf(sv.z + uk + vv.z - nrm);
      o.w = __expf(sv.w + uk + vv.w - nrm);
      *(float4*)&Ps[k][c4] = o;
    }
  }
  __syncthreads();
  int tc = tid & 31, tk = tid >> 5;
  int c0 = tc << 2, k0 = tk << 3;
  float acc[4][8];
  #pragma unroll
  for (int i = 0; i < 4; ++i)
    #pragma unroll
    for (int kk = 0; kk < 8; ++kk) acc[i][kk] = 0.f;
  for (int n = 0; n < 64; ++n) {
    float4 f = *(const float4*)&Fs[n][c0];
    float pv[8];
    #pragma unroll
    for (int kk = 0; kk < 8; ++kk) pv[kk] = Ps[k0 + kk][n];
    #pragma unroll
    for (int i = 0; i < 4; ++i) {
      float fv = ((const float*)&f)[i];
      #pragma unroll
      for (int kk = 0; kk < 8; ++kk) acc[i][kk] += fv * pv[kk];
    }
  }
  float* dst = partial + ((size_t)(b * 64 + j) << 13);
  #pragma unroll
  for (int i = 0; i < 4; ++i) {
    float4 lo = {acc[i][0], acc[i][1], acc[i][2], acc[i][3]};
    float4 hi = {acc[i][4], acc[i][5], acc[i][6], acc[i][7]};
    *(float4*)&dst[((c0 + i) << 6) + k0] = lo;
    *(float4*)&dst[((c0 + i) << 6) + k0 + 4] = hi;
  }
}

// ---------------- pooled stage 2: reduce 64 partials, coalesced ----------------
__global__ void k_pooled2(const float* __restrict__ partial, float* __restrict__ pooled) {
  int o = blockIdx.x * 256 + threadIdx.x;
  int b = o >> 13, rem = o & 8191;
  const float* src = partial + ((size_t)b << 19) + rem;
  float s = 0.f;
  #pragma unroll 8
  for (int j = 0; j < 64; ++j) s += src[(size_t)j << 13];
  pooled[o] = s;
}

// ---------------- patch output: l2norm over c (128), write [b][c*64+k] --------------
__global__ void k_patch_out(const float* __restrict__ pooled, float* __restrict__ out) {
  int b = blockIdx.x >> 6, k = blockIdx.x & 63;
  int tid = threadIdx.x;
  float v0 = pooled[((size_t)(b * 128) + tid) * MD + k];
  float v1 = pooled[((size_t)(b * 128) + 64 + tid) * MD + k];
  float ss = v0 * v0 + v1 * v1;
  #pragma unroll
  for (int o = 32; o; o >>= 1) ss += __shfl_down(ss, o);
  ss = __shfl(ss, 0);
  float inv = 1.f / fmaxf(sqrtf(ss), 1e-12f);
  out[(size_t)b * 8704 + tid * 64 + k] = v0 * inv;
  out[(size_t)b * 8704 + (64 + tid) * 64 + k] = v1 * inv;
}

// ---------------- workspace layout (bytes) ----------------
#define OFF_ABF 0u
#define OFF_SC 0u                         // B*64*4096*4 (compact, no dust row)
#define OFF_U 4259840u
#define OFF_V 4263936u
#define OFF_POOL 8523776u
#define OFF_HP 8982528u                   // written post-GEMM2 only!
#define OFF_H 67108864u
#define OFF_PART OFF_H
#define OFF_CP1 75497472u
#define OFF_CP2 83886080u
#define OFF_BT1CR 88080384u
#define OFF_BT2CR 96468992u
#define OFF_ACR 98566144u
#define OFF_A2 99090432u
#define OFF_FS 100663296u
#define OFF_W1T 117440512u
#define OFF_W2T 121634816u
#define OFF_B1C 122159104u
#define OFF_B2C 122163200u

extern "C" void kernel_launch(void* const* d_in, const int* in_sizes, int n_in,
                              void* d_out, int out_size, void* d_ws, size_t ws_size,
                              hipStream_t stream) {
  (void)in_sizes; (void)n_in; (void)out_size; (void)ws_size;
  const float* tokens = (const float*)d_in[0];
  const float* cam_w1 = (const float*)d_in[2];
  const float* cam_b1 = (const float*)d_in[3];
  const float* cam_w2 = (const float*)d_in[4];
  const float* cam_b2 = (const float*)d_in[5];
  const float* cam_p  = (const float*)d_in[6];
  const float* cam_w3 = (const float*)d_in[7];
  const float* cam_b3 = (const float*)d_in[8];
  const float* cam_w4 = (const float*)d_in[9];
  const float* cam_b4 = (const float*)d_in[10];
  const float* reg_w1 = (const float*)d_in[11];
  const float* reg_b1 = (const float*)d_in[12];
  const float* reg_w2 = (const float*)d_in[13];
  const float* reg_b2 = (const float*)d_in[14];
  const float* reg_p  = (const float*)d_in[15];
  const float* reg_w3 = (const float*)d_in[16];
  const float* reg_b3 = (const float*)d_in[17];
  const float* reg_w4 = (const float*)d_in[18];
  const float* reg_b4 = (const float*)d_in[19];
  const float* pf_w1  = (const float*)d_in[20];
  const float* pf_b1  = (const float*)d_in[21];
  const float* pf_w2  = (const float*)d_in[22];
  const float* pf_b2  = (const float*)d_in[23];
  const float* ps_w1  = (const float*)d_in[24];
  const float* ps_b1  = (const float*)d_in[25];
  const float* ps_w2  = (const float*)d_in[26];
  const float* ps_b2  = (const float*)d_in[27];
  const float* dust   = (const float*)d_in[28];
  float* out = (float*)d_out;
  char* ws = (char*)d_ws;

  u16* Abf = (u16*)(ws + OFF_ABF);
  float* Sc = (float*)(ws + OFF_SC);
  float* ub = (float*)(ws + OFF_U);
  float* vb = (float*)(ws + OFF_V);
  float* pooled = (float*)(ws + OFF_POOL);
  float* hp = (float*)(ws + OFF_HP);
  u16* H   = (u16*)(ws + OFF_H);
  float* partial = (float*)(ws + OFF_PART);
  float* cp1 = (float*)(ws + OFF_CP1);
  float* cp2 = (float*)(ws + OFF_CP2);
  u16* Bt1cr = (u16*)(ws + OFF_BT1CR);
  u16* Bt2cr = (u16*)(ws + OFF_BT2CR);
  u16* Acr = (u16*)(ws + OFF_ACR);
  u16* A2  = (u16*)(ws + OFF_A2);
  float* FS = (float*)(ws + OFF_FS);
  u16* W1t = (u16*)(ws + OFF_W1T);
  u16* W2t = (u16*)(ws + OFF_W2T);
  float* b1c = (float*)(ws + OFF_B1C);
  float* b2c = (float*)(ws + OFF_B2C);

  hipMemsetAsync(vb, 0, (size_t)B_ * NPB * sizeof(float), stream);

  // ---- patch prep (convert + packs merged) + GEMMs ----
  k_prep_patch<<<18692, 256, 0, stream>>>(tokens, Abf, pf_w1, ps_w1, pf_w2, ps_w2,
                                          pf_b1, ps_b1, pf_b2, ps_b2,
                                          W1t, W2t, b1c, b2c);
  k_gemm<1, 1, 0><<<dim3(128, 8), 256, 0, stream>>>(Abf, W1t, b1c, (void*)H,
                                                    MROWS, N1, CDIM, nullptr);
  k_gemm<0, 0, 1><<<dim3(128, 2), 256, 0, stream>>>(H, W2t, b2c, (void*)FS,
                                                    MROWS, N2, N1, Sc);

  // ---- cam/reg path (Abf and H regions now dead) ----
  k_pack_cr<<<5248, 256, 0, stream>>>(cam_w1, reg_w1, cam_w2, reg_w2, tokens,
                                      Bt1cr, Bt2cr, Acr);
  k_gemm_splitk<<<dim3(1, 16, 8), 256, 0, stream>>>(Acr, Bt1cr, cp1, 2048, CDIM, 256);
  k_cr_fin1<<<dim3(128, 4), 256, 0, stream>>>(cp1, cam_b1, reg_b1, A2);
  k_gemm_splitk<<<dim3(1, 8, 8), 256, 0, stream>>>(A2, Bt2cr, cp2, 1024, N1, 128);
  k_cr_fin2<<<80, 512, 0, stream>>>(cp2, cam_b2, reg_b2, cam_p, reg_p, hp);
  k_cr3f<<<8, 512, 0, stream>>>(hp, cam_p, cam_w3, cam_b3, cam_w4, cam_b4,
                                reg_p, reg_w3, reg_b3, reg_w4, reg_b4, out);

  // ---- sinkhorn (dust row virtual) + pooled + outputs ----
  for (int it = 0; it < 3; ++it) {
    k_sink_u<<<B_ * MA, 256, 0, stream>>>(Sc, vb, ub, dust);
    k_sink_v<<<B_ * 16, 256, 0, stream>>>(Sc, ub, vb, dust);
  }
  k_pooled1<<<B_ * 64, 256, 0, stream>>>(FS, Sc, ub, vb, partial);
  k_pooled2<<<128, 256, 0, stream>>>(partial, pooled);
  k_patch_out<<<B_ * MD, 64, 0, stream>>>(pooled, out);
}

// Round 18
// 238.152 us; speedup vs baseline: 1.1306x; 1.1306x over previous
//
#include <hip/hip_runtime.h>

typedef unsigned short u16;
typedef unsigned int u32;

#define B_ 4
#define S_ 4
#define NTOK 1029
#define CDIM 2048
#define PSI 5
#define NPB 4096
#define MROWS 16384
#define N1 1024
#define N2 256
#define MD 64
#define MA 65

using bf16x8 = __attribute__((ext_vector_type(8))) short;
using f32x4  = __attribute__((ext_vector_type(4))) float;
using u16x8  = __attribute__((ext_vector_type(8))) unsigned short;

typedef __attribute__((address_space(1))) const void global_cvoid;
typedef __attribute__((address_space(3))) void lds_void;

__device__ __forceinline__ u16 f2b(float f) {
  u32 u = __builtin_bit_cast(u32, f);
  u32 r = (u + 0x7fffu + ((u >> 16) & 1u)) >> 16;
  return (u16)r;
}

// ---------------- merged prep: patch convert (fp32->bf16) + W1t/W2t/bias packs -------
__global__ void k_prep_patch(const float* __restrict__ tokens, u16* __restrict__ Abf,
                             const float* __restrict__ pfw1, const float* __restrict__ psw1,
                             const float* __restrict__ pfw2, const float* __restrict__ psw2,
                             const float* __restrict__ pfb1, const float* __restrict__ psb1,
                             const float* __restrict__ pfb2, const float* __restrict__ psb2,
                             u16* __restrict__ W1t, u16* __restrict__ W2t,
                             float* __restrict__ b1c, float* __restrict__ b2c) {
  __shared__ float tile[32][33];
  int id = blockIdx.x, tid = threadIdx.x;
  if (id < 16384) {
    size_t idx = (size_t)id * 256 + tid;
    size_t r = idx >> 8;
    int cv = (int)(idx & 255) << 3;
    int b = (int)(r >> 12), s = (int)((r >> 10) & 3), j = (int)(r & 1023);
    const float* src = tokens + ((size_t)((b * S_ + s) * NTOK + PSI + j)) * CDIM + cv;
    float4 v0 = *(const float4*)src;
    float4 v1 = *(const float4*)(src + 4);
    u16x8 o;
    o[0] = f2b(v0.x); o[1] = f2b(v0.y); o[2] = f2b(v0.z); o[3] = f2b(v0.w);
    o[4] = f2b(v1.x); o[5] = f2b(v1.y); o[6] = f2b(v1.z); o[7] = f2b(v1.w);
    *(u16x8*)(Abf + r * CDIM + cv) = o;
    return;
  }
  int id2 = id - 16384;
  int tx = tid & 31, ty = tid >> 5;
  if (id2 < 2048) {
    int kb = (id2 & 63) * 32, nb = (id2 >> 6) * 32;
    #pragma unroll
    for (int i = 0; i < 4; ++i) {
      int k = kb + ty + i * 8, n = nb + tx;
      tile[ty + i * 8][tx] = (n < 512) ? pfw1[(size_t)k * 512 + n] : psw1[(size_t)k * 512 + (n - 512)];
    }
    __syncthreads();
    #pragma unroll
    for (int i = 0; i < 4; ++i) {
      int n = nb + ty + i * 8, k = kb + tx;
      W1t[(size_t)n * CDIM + k] = f2b(tile[tx][ty + i * 8]);
    }
  } else if (id2 < 2304) {
    int i2 = id2 - 2048;
    int kb = (i2 & 31) * 32, jb = (i2 >> 5) * 32;
    #pragma unroll
    for (int i = 0; i < 4; ++i) {
      int k = kb + ty + i * 8, j = jb + tx;
      float v = 0.f;
      if (j < 128) { if (k < 512) v = pfw2[(size_t)k * 128 + j]; }
      else if (j < 192) { if (k >= 512) v = psw2[(size_t)(k - 512) * 64 + (j - 128)]; }
      tile[ty + i * 8][tx] = v;
    }
    __syncthreads();
    #pragma unroll
    for (int i = 0; i < 4; ++i) {
      int j = jb + ty + i * 8, k = kb + tx;
      W2t[(size_t)j * N1 + k] = f2b(tile[tx][ty + i * 8]);
    }
  } else {
    int t = (id2 - 2304) * 256 + tid;
    if (t < 1024) b1c[t] = (t < 512) ? pfb1[t] : psb1[t - 512];
    if (t < 256)  b2c[t] = (t < 128) ? pfb2[t] : ((t < 192) ? psb2[t - 128] : 0.f);
  }
}

// ---------------- merged cr-side packs: Bt1cr, Bt2cr, Acr ----------------
__global__ void k_pack_cr(const float* __restrict__ camw1, const float* __restrict__ regw1,
                          const float* __restrict__ camw2, const float* __restrict__ regw2,
                          const float* __restrict__ tokens,
                          u16* __restrict__ Bt1cr, u16* __restrict__ Bt2cr,
                          u16* __restrict__ Acr) {
  __shared__ float tile[32][33];
  int id = blockIdx.x, tid = threadIdx.x;
  int tx = tid & 31, ty = tid >> 5;
  if (id < 4096) {
    const float* src = (id < 2048) ? camw1 : regw1;
    u16* dst = Bt1cr + ((id < 2048) ? 0 : (size_t)1024 * CDIM);
    int i2 = id & 2047;
    int kb = (i2 & 63) * 32, nb = (i2 >> 6) * 32;
    #pragma unroll
    for (int i = 0; i < 4; ++i)
      tile[ty + i * 8][tx] = src[(size_t)(kb + ty + i * 8) * 1024 + nb + tx];
    __syncthreads();
    #pragma unroll
    for (int i = 0; i < 4; ++i)
      dst[(size_t)(nb + ty + i * 8) * CDIM + kb + tx] = f2b(tile[tx][ty + i * 8]);
  } else if (id < 5120) {
    int i3 = id - 4096;
    const float* src = (i3 < 512) ? camw2 : regw2;
    u16* dst = Bt2cr + ((i3 < 512) ? 0 : (size_t)512 * N1);
    int i2 = i3 & 511;
    int kb = (i2 & 31) * 32, nb = (i2 >> 5) * 32;
    #pragma unroll
    for (int i = 0; i < 4; ++i)
      tile[ty + i * 8][tx] = src[(size_t)(kb + ty + i * 8) * 512 + nb + tx];
    __syncthreads();
    #pragma unroll
    for (int i = 0; i < 4; ++i)
      dst[(size_t)(nb + ty + i * 8) * N1 + kb + tx] = f2b(tile[tx][ty + i * 8]);
  } else {
    int r = id - 5120;
    int c0 = tid << 3;
    u16x8 o;
    if (r >= 80) {
      #pragma unroll
      for (int i = 0; i < 8; ++i) o[i] = 0;
    } else {
      const float* src;
      if (r < 16) { int b = r >> 2, s = r & 3; src = tokens + ((size_t)(b * S_ + s) * NTOK) * CDIM; }
      else { int r2 = r - 16; int b = r2 >> 4, q = r2 & 15, s = q >> 2, t = (q & 3) + 1;
             src = tokens + ((size_t)(b * S_ + s) * NTOK + t) * CDIM; }
      float4 v0 = *(const float4*)(src + c0);
      float4 v1 = *(const float4*)(src + c0 + 4);
      o[0] = f2b(v0.x); o[1] = f2b(v0.y); o[2] = f2b(v0.z); o[3] = f2b(v0.w);
      o[4] = f2b(v1.x); o[5] = f2b(v1.y); o[6] = f2b(v1.z); o[7] = f2b(v1.w);
    }
    *(u16x8*)(Acr + (size_t)r * CDIM + c0) = o;
  }
}

// ---------------- bf16 MFMA GEMM: 2-buf, counted vmcnt(8), raw barriers, T2 swizzle --
#define STAGE_TILE(buf, k0)                                                    \
  {                                                                            \
    _Pragma("unroll")                                                          \
    for (int r = 0; r < 4; ++r) {                                              \
      __builtin_amdgcn_global_load_lds(                                        \
          (global_cvoid*)(A + abase + (size_t)(r * 32) * K + (k0)),            \
          (lds_void*)(&As[buf][lofs + r * 2048]), 16, 0, 0);                   \
      __builtin_amdgcn_global_load_lds(                                        \
          (global_cvoid*)(Bt + bbase + (size_t)(r * 32) * K + (k0)),           \
          (lds_void*)(&Bs[buf][lofs + r * 2048]), 16, 0, 0);                   \
    }                                                                          \
  }

#define COMPUTE_TILE(buf)                                                      \
  {                                                                            \
    _Pragma("unroll")                                                          \
    for (int kk = 0; kk < 64; kk += 32) {                                      \
      const int csw = (kk + hi8) ^ ((lane & 7) << 3);                          \
      bf16x8 af[4], bfr[4];                                                    \
      _Pragma("unroll")                                                        \
      for (int i = 0; i < 4; ++i) {                                            \
        af[i]  = *(const bf16x8*)&As[buf][((wr << 6) + (i << 4) + (lane & 15)) * 64 + csw]; \
        bfr[i] = *(const bf16x8*)&Bs[buf][((wc << 6) + (i << 4) + (lane & 15)) * 64 + csw]; \
      }                                                                        \
      _Pragma("unroll")                                                        \
      for (int mi = 0; mi < 4; ++mi)                                           \
        _Pragma("unroll")                                                      \
        for (int ni = 0; ni < 4; ++ni)                                         \
          acc[mi][ni] = __builtin_amdgcn_mfma_f32_16x16x32_bf16(af[mi], bfr[ni], acc[mi][ni], 0, 0, 0); \
    }                                                                          \
  }

template <int RELU, int OUTBF, int WRSC>
__global__ __launch_bounds__(256, 2)
void k_gemm(const u16* __restrict__ A, const u16* __restrict__ Bt,
            const float* __restrict__ bias, void* __restrict__ Cout,
            int M, int N, int K, float* __restrict__ ScOut) {
  __shared__ u16 As[2][128 * 64];
  __shared__ u16 Bs[2][128 * 64];
  const int tid = threadIdx.x;
  const int lane = tid & 63;
  const int wave = tid >> 6;
  const int tM = blockIdx.x << 7;
  const int tN = blockIdx.y << 7;
  const int wr = wave >> 1, wc = wave & 1;
  const int hi8 = (lane >> 4) << 3;

  const int srow = (wave << 3) + (lane >> 3);
  const int scolsw = ((lane & 7) ^ (lane >> 3)) << 3;
  const size_t abase = (size_t)(tM + srow) * K + scolsw;
  const size_t bbase = (size_t)(tN + srow) * K + scolsw;
  const int lofs = (wave << 9) + (lane << 3);

  f32x4 acc[4][4];
  #pragma unroll
  for (int i = 0; i < 4; ++i)
    #pragma unroll
    for (int j = 0; j < 4; ++j)
      acc[i][j] = (f32x4){0.f, 0.f, 0.f, 0.f};

  const int nt = K >> 6;
  STAGE_TILE(0, 0)
  STAGE_TILE(1, 64)
  for (int t = 0; t < nt; t += 2) {
    asm volatile("s_waitcnt vmcnt(8)" ::: "memory");
    __builtin_amdgcn_s_barrier();
    COMPUTE_TILE(0)
    __builtin_amdgcn_s_barrier();
    if (t + 2 < nt) STAGE_TILE(0, (t + 2) << 6)
    if (t + 1 == nt - 1) {
      asm volatile("s_waitcnt vmcnt(0)" ::: "memory");
    } else {
      asm volatile("s_waitcnt vmcnt(8)" ::: "memory");
    }
    __builtin_amdgcn_s_barrier();
    COMPUTE_TILE(1)
    __builtin_amdgcn_s_barrier();
    if (t + 3 < nt) STAGE_TILE(1, (t + 3) << 6)
  }

  #pragma unroll
  for (int ni = 0; ni < 4; ++ni) {
    const int col = tN + (wc << 6) + (ni << 4) + (lane & 15);
    const float bv = bias[col];
    #pragma unroll
    for (int mi = 0; mi < 4; ++mi) {
      #pragma unroll
      for (int j = 0; j < 4; ++j) {
        const int row = tM + (wr << 6) + (mi << 4) + ((lane >> 4) << 2) + j;
        float vv = acc[mi][ni][j] + bv;
        if (RELU) vv = fmaxf(vv, 0.f);
        if (OUTBF) ((u16*)Cout)[(size_t)row * N + col] = f2b(vv);
        else       ((float*)Cout)[(size_t)row * N + col] = vv;
        if (WRSC) {
          if (col >= 128 && col < 192)
            ScOut[((size_t)((row >> 12) * MD + (col - 128))) * NPB + (row & 4095)] = vv;
        }
      }
    }
  }
}

// ---------------- split-K MFMA GEMM, M=128 fixed (single-buffer, known-good) ----
__global__ __launch_bounds__(256, 2)
void k_gemm_splitk(const u16* __restrict__ A, const u16* __restrict__ Bt,
                   float* __restrict__ part, int N, int K, int KC) {
  __shared__ u16 As1[128 * 64];
  __shared__ u16 Bs1[128 * 64];
  const int tid = threadIdx.x;
  const int lane = tid & 63;
  const int wave = tid >> 6;
  const int tN = blockIdx.y << 7;
  const int kb = blockIdx.z * KC;
  const int wr = wave >> 1, wc = wave & 1;
  const int srow = (wave << 3) + (lane >> 3);
  const int scol = (lane & 7) << 3;
  const size_t abase = (size_t)srow * K + scol;
  const size_t bbase = (size_t)(tN + srow) * K + scol;
  u16* asw = &As1[(wave << 9) + (lane << 3)];
  u16* bsw = &Bs1[(wave << 9) + (lane << 3)];

  f32x4 acc[4][4];
  #pragma unroll
  for (int i = 0; i < 4; ++i)
    #pragma unroll
    for (int j = 0; j < 4; ++j)
      acc[i][j] = (f32x4){0.f, 0.f, 0.f, 0.f};

  for (int k0 = kb; k0 < kb + KC; k0 += 64) {
    #pragma unroll
    for (int r = 0; r < 4; ++r) {
      __builtin_amdgcn_global_load_lds(
          (global_cvoid*)(A + abase + (size_t)(r * 32) * K + k0),
          (lds_void*)(asw + r * 2048), 16, 0, 0);
      __builtin_amdgcn_global_load_lds(
          (global_cvoid*)(Bt + bbase + (size_t)(r * 32) * K + k0),
          (lds_void*)(bsw + r * 2048), 16, 0, 0);
    }
    __syncthreads();
    #pragma unroll
    for (int kk = 0; kk < 64; kk += 32) {
      bf16x8 af[4], bfr[4];
      #pragma unroll
      for (int i = 0; i < 4; ++i) {
        af[i]  = *(const bf16x8*)&As1[((wr << 6) + (i << 4) + (lane & 15)) * 64 + kk + ((lane >> 4) << 3)];
        bfr[i] = *(const bf16x8*)&Bs1[((wc << 6) + (i << 4) + (lane & 15)) * 64 + kk + ((lane >> 4) << 3)];
      }
      #pragma unroll
      for (int mi = 0; mi < 4; ++mi)
        #pragma unroll
        for (int ni = 0; ni < 4; ++ni)
          acc[mi][ni] = __builtin_amdgcn_mfma_f32_16x16x32_bf16(af[mi], bfr[ni], acc[mi][ni], 0, 0, 0);
    }
    __syncthreads();
  }

  float* dst = part + (size_t)blockIdx.z * 128 * N;
  #pragma unroll
  for (int ni = 0; ni < 4; ++ni) {
    const int col = tN + (wc << 6) + (ni << 4) + (lane & 15);
    #pragma unroll
    for (int mi = 0; mi < 4; ++mi) {
      #pragma unroll
      for (int j = 0; j < 4; ++j) {
        const int row = (wr << 6) + (mi << 4) + ((lane >> 4) << 2) + j;
        dst[(size_t)row * N + col] = acc[mi][ni][j];
      }
    }
  }
}

// ---------------- cr fin1: reduce part1(kc=8) + bias + relu -> A2 bf16 [128][1024] ----
__global__ void k_cr_fin1(const float* __restrict__ part1,
                          const float* __restrict__ camb1, const float* __restrict__ regb1,
                          u16* __restrict__ A2) {
  int r = blockIdx.x;
  int j = blockIdx.y * 256 + threadIdx.x;
  if (r >= 80) { A2[(size_t)r * N1 + j] = 0; return; }
  bool cam = (r < 16);
  int cm = j + (cam ? 0 : 1024);
  float s = 0.f;
  #pragma unroll
  for (int kc = 0; kc < 8; ++kc) s += part1[((size_t)kc * 128 + r) * 2048 + cm];
  s += cam ? camb1[j] : regb1[j];
  A2[(size_t)r * N1 + j] = f2b(fmaxf(s, 0.f));
}

// ---------------- cr fin2: reduce part2(kc=8) + bias + l2norm + clip^p -> hp[80][512] -
__global__ __launch_bounds__(512)
void k_cr_fin2(const float* __restrict__ part2,
               const float* __restrict__ camb2, const float* __restrict__ regb2,
               const float* __restrict__ camp, const float* __restrict__ regp,
               float* __restrict__ hp) {
  __shared__ float red[8];
  int r = blockIdx.x;
  int j = threadIdx.x;
  bool cam = (r < 16);
  int cm = j + (cam ? 0 : 512);
  float s = 0.f;
  #pragma unroll
  for (int kc = 0; kc < 8; ++kc) s += part2[((size_t)kc * 128 + r) * 1024 + cm];
  s += cam ? camb2[j] : regb2[j];
  float ss = s * s;
  #pragma unroll
  for (int o = 32; o; o >>= 1) ss += __shfl_down(ss, o);
  if ((j & 63) == 0) red[j >> 6] = ss;
  __syncthreads();
  float tot = 0.f;
  #pragma unroll
  for (int i = 0; i < 8; ++i) tot += red[i];
  float inv = 1.f / fmaxf(sqrtf(tot), 1e-12f);
  float t = fmaxf(s * inv, 1e-6f);
  hp[(size_t)r * 512 + j] = powf(t, cam ? camp[0] : regp[0]);
}

// ---------------- cr3a: GeM finalize -> gsb[8][512] ----------------
__global__ __launch_bounds__(512)
void k_cr3a(const float* __restrict__ hp, const float* __restrict__ camp,
            const float* __restrict__ regp, float* __restrict__ gsb) {
  int pb = blockIdx.x;
  bool cam = (pb < 4);
  int b = pb & 3;
  float p = cam ? camp[0] : regp[0];
  int L = cam ? 4 : 16;
  int row0 = cam ? b * 4 : 16 + b * 16;
  int o = threadIdx.x;
  float s = 0.f;
  for (int r = 0; r < L; ++r) s += hp[(size_t)(row0 + r) * 512 + o];
  gsb[pb * 512 + o] = powf(s / (float)L, 1.f / p);
}

// ---------------- cr3b: o1[8][512] = ReLU(gs @ W3 + b3), k-split x4 ----------------
__global__ __launch_bounds__(512)
void k_cr3b(const float* __restrict__ gsb,
            const float* __restrict__ camw3, const float* __restrict__ regw3,
            const float* __restrict__ camb3, const float* __restrict__ regb3,
            float* __restrict__ o1b) {
  __shared__ float gls[512];
  __shared__ float part[4][128];
  int pb = blockIdx.x, och = blockIdx.y;
  bool cam = (pb < 4);
  const float* W3 = cam ? camw3 : regw3;
  const float* B3 = cam ? camb3 : regb3;
  int tid = threadIdx.x;
  gls[tid] = gsb[pb * 512 + tid];
  __syncthreads();
  int col = tid & 127, kq = tid >> 7;
  int o = (och << 7) + col;
  float acc = 0.f;
  const float* w = W3 + (size_t)(kq << 7) * 512 + o;
  #pragma unroll 8
  for (int kk = 0; kk < 128; ++kk) acc += gls[(kq << 7) + kk] * w[(size_t)kk * 512];
  part[kq][col] = acc;
  __syncthreads();
  if (kq == 0) {
    float s = part[0][col] + part[1][col] + part[2][col] + part[3][col] + B3[o];
    o1b[pb * 512 + o] = fmaxf(s, 0.f);
  }
}

// ---------------- cr3c: out = l2norm(o1 @ W4 + b4), k-split x2 + block l2norm -------
__global__ __launch_bounds__(512)
void k_cr3c(const float* __restrict__ o1b,
            const float* __restrict__ camw4, const float* __restrict__ regw4,
            const float* __restrict__ camb4, const float* __restrict__ regb4,
            float* __restrict__ out) {
  __shared__ float o1s[512];
  __shared__ float part[2][256];
  __shared__ float vsq[256];
  __shared__ float red[4];
  int pb = blockIdx.x;
  bool cam = (pb < 4);
  int path = pb >> 2, b = pb & 3;
  const float* W4 = cam ? camw4 : regw4;
  const float* B4 = cam ? camb4 : regb4;
  int tid = threadIdx.x;
  o1s[tid] = o1b[pb * 512 + tid];
  __syncthreads();
  int col = tid & 255, kh = tid >> 8;
  float acc = 0.f;
  const float* w = W4 + (size_t)(kh << 8) * 256 + col;
  #pragma unroll 8
  for (int kk = 0; kk < 256; ++kk) acc += o1s[(kh << 8) + kk] * w[(size_t)kk * 256];
  part[kh][col] = acc;
  __syncthreads();
  float val = 0.f;
  if (kh == 0) {
    val = part[0][col] + part[1][col] + B4[col];
    vsq[col] = val * val;
  }
  __syncthreads();
  float ss = (tid < 256) ? vsq[tid] : 0.f;
  #pragma unroll
  for (int o = 32; o; o >>= 1) ss += __shfl_down(ss, o);
  if (tid < 256 && (tid & 63) == 0) red[tid >> 6] = ss;
  __syncthreads();
  if (kh == 0) {
    float tot = red[0] + red[1] + red[2] + red[3];
    float inv = 1.f / fmaxf(sqrtf(tot), 1e-12f);
    out[(size_t)b * 8704 + 8192 + path * 256 + col] = val * inv;
  }
}

// ---------------- sinkhorn: u update — online LSE; dust row k==64 is virtual ---------
__global__ void k_sink_u(const float* __restrict__ Sc, const float* __restrict__ v,
                         float* __restrict__ u, const float* __restrict__ dust) {
  __shared__ float redm[4], reds[4];
  int b = blockIdx.x / MA, k = blockIdx.x % MA;
  const float* vb = v + (size_t)b * NPB;
  int tid = threadIdx.x;
  float mx = -1e30f, s = 0.f;
  if (k < MD) {
    const float* row = Sc + ((size_t)(b * MD) + k) * NPB;
    for (int n = tid; n < NPB; n += 256) {
      float x = row[n] + vb[n];
      float m2 = fmaxf(mx, x);
      s = s * __expf(mx - m2) + __expf(x - m2);
      mx = m2;
    }
  } else {
    float d0 = dust[0];
    for (int n = tid; n < NPB; n += 256) {
      float x = d0 + vb[n];
      float m2 = fmaxf(mx, x);
      s = s * __expf(mx - m2) + __expf(x - m2);
      mx = m2;
    }
  }
  #pragma unroll
  for (int o = 32; o; o >>= 1) {
    float mo = __shfl_down(mx, o), so = __shfl_down(s, o);
    float m2 = fmaxf(mx, mo);
    s = s * __expf(mx - m2) + so * __expf(mo - m2);
    mx = m2;
  }
  if ((tid & 63) == 0) { redm[tid >> 6] = mx; reds[tid >> 6] = s; }
  __syncthreads();
  if (tid == 0) {
    float M = redm[0];
    #pragma unroll
    for (int i = 1; i < 4; ++i) M = fmaxf(M, redm[i]);
    float S = 0.f;
    #pragma unroll
    for (int i = 0; i < 4; ++i) S += reds[i] * __expf(redm[i] - M);
    const float nrm = -logf((float)(NPB + MD));
    float la = (k == MD) ? (nrm + logf((float)(NPB - MD))) : nrm;
    u[b * MA + k] = la - (M + __logf(S));
  }
}

// ---------------- sinkhorn: v update (col LSE over 64 Sc rows + virtual dust) --------
__global__ void k_sink_v(const float* __restrict__ Sc, const float* __restrict__ u,
                         float* __restrict__ v, const float* __restrict__ dust) {
  __shared__ float us[MA];
  int b = blockIdx.x >> 4;
  int n = ((blockIdx.x & 15) << 8) + threadIdx.x;
  if (threadIdx.x < MA) us[threadIdx.x] = u[b * MA + threadIdx.x];
  __syncthreads();
  const float* Sb = Sc + (size_t)b * MD * NPB + n;
  float d0 = dust[0];
  float mx = d0 + us[MD];
  for (int k = 0; k < MD; ++k) mx = fmaxf(mx, Sb[(size_t)k * NPB] + us[k]);
  float s = __expf(d0 + us[MD] - mx);
  for (int k = 0; k < MD; ++k) s += __expf(Sb[(size_t)k * NPB] + us[k] - mx);
  const float nrm = -logf((float)(NPB + MD));
  v[(size_t)b * NPB + n] = nrm - (mx + __logf(s));
}

// ---------------- pooled stage 1 (P fused): partial[b][j][c][k] over 64-n chunks ------
__global__ __launch_bounds__(256)
void k_pooled1(const float* __restrict__ FS, const float* __restrict__ Sc,
               const float* __restrict__ u, const float* __restrict__ v,
               float* __restrict__ partial) {
  __shared__ float Fs[64][132];
  __shared__ float Ps[64][68];
  int b = blockIdx.x >> 6, j = blockIdx.x & 63;
  int n0 = j << 6;
  int tid = threadIdx.x;
  {
    int r = tid >> 5;
    int c4 = (tid & 31) << 2;
    #pragma unroll
    for (int i = 0; i < 8; ++i) {
      int n = r + (i << 3);
      float4 vv = *(const float4*)&FS[((size_t)(b * NPB + n0 + n)) * N2 + c4];
      *(float4*)&Fs[n][c4] = vv;
    }
  }
  {
    const float nrm = -logf((float)(NPB + MD));
    int r = tid >> 4;
    int c4 = (tid & 15) << 2;
    #pragma unroll
    for (int i = 0; i < 4; ++i) {
      int k = r + (i << 4);
      float uk = u[b * MA + k];
      float4 sv = *(const float4*)&Sc[((size_t)(b * MD) + k) * NPB + n0 + c4];
      float4 vv = *(const float4*)&v[(size_t)b * NPB + n0 + c4];
      float4 o;
      o.x = __expf(sv.x + uk + vv.x - nrm);
      o.y = __expf(sv.y + uk + vv.y - nrm);
      o.z = __expf(sv.z + uk + vv.z - nrm);
      o.w = __expf(sv.w + uk + vv.w - nrm);
      *(float4*)&Ps[k][c4] = o;
    }
  }
  __syncthreads();
  int tc = tid & 31, tk = tid >> 5;
  int c0 = tc << 2, k0 = tk << 3;
  float acc[4][8];
  #pragma unroll
  for (int i = 0; i < 4; ++i)
    #pragma unroll
    for (int kk = 0; kk < 8; ++kk) acc[i][kk] = 0.f;
  for (int n = 0; n < 64; ++n) {
    float4 f = *(const float4*)&Fs[n][c0];
    float pv[8];
    #pragma unroll
    for (int kk = 0; kk < 8; ++kk) pv[kk] = Ps[k0 + kk][n];
    #pragma unroll
    for (int i = 0; i < 4; ++i) {
      float fv = ((const float*)&f)[i];
      #pragma unroll
      for (int kk = 0; kk < 8; ++kk) acc[i][kk] += fv * pv[kk];
    }
  }
  float* dst = partial + ((size_t)(b * 64 + j) << 13);
  #pragma unroll
  for (int i = 0; i < 4; ++i) {
    float4 lo = {acc[i][0], acc[i][1], acc[i][2], acc[i][3]};
    float4 hi = {acc[i][4], acc[i][5], acc[i][6], acc[i][7]};
    *(float4*)&dst[((c0 + i) << 6) + k0] = lo;
    *(float4*)&dst[((c0 + i) << 6) + k0 + 4] = hi;
  }
}

// ---------------- pooled stage 2: reduce 64 partials, coalesced ----------------
__global__ void k_pooled2(const float* __restrict__ partial, float* __restrict__ pooled) {
  int o = blockIdx.x * 256 + threadIdx.x;
  int b = o >> 13, rem = o & 8191;
  const float* src = partial + ((size_t)b << 19) + rem;
  float s = 0.f;
  #pragma unroll 8
  for (int j = 0; j < 64; ++j) s += src[(size_t)j << 13];
  pooled[o] = s;
}

// ---------------- patch output: l2norm over c (128), write [b][c*64+k] --------------
__global__ void k_patch_out(const float* __restrict__ pooled, float* __restrict__ out) {
  int b = blockIdx.x >> 6, k = blockIdx.x & 63;
  int tid = threadIdx.x;
  float v0 = pooled[((size_t)(b * 128) + tid) * MD + k];
  float v1 = pooled[((size_t)(b * 128) + 64 + tid) * MD + k];
  float ss = v0 * v0 + v1 * v1;
  #pragma unroll
  for (int o = 32; o; o >>= 1) ss += __shfl_down(ss, o);
  ss = __shfl(ss, 0);
  float inv = 1.f / fmaxf(sqrtf(ss), 1e-12f);
  out[(size_t)b * 8704 + tid * 64 + k] = v0 * inv;
  out[(size_t)b * 8704 + (64 + tid) * 64 + k] = v1 * inv;
}

// ---------------- workspace layout (bytes) ----------------
#define OFF_ABF 0u
#define OFF_SC 0u                         // B*64*4096*4 (compact, no dust row)
#define OFF_U 4259840u
#define OFF_V 4263936u
#define OFF_POOL 8523776u
#define OFF_HP 8982528u                   // written post-GEMM2 only!
#define OFF_H 67108864u
#define OFF_PART OFF_H
#define OFF_CP1 75497472u
#define OFF_GSB OFF_CP1
#define OFF_O1B 75513856u
#define OFF_CP2 83886080u
#define OFF_BT1CR 88080384u
#define OFF_BT2CR 96468992u
#define OFF_ACR 98566144u
#define OFF_A2 99090432u
#define OFF_FS 100663296u
#define OFF_W1T 117440512u
#define OFF_W2T 121634816u
#define OFF_B1C 122159104u
#define OFF_B2C 122163200u

extern "C" void kernel_launch(void* const* d_in, const int* in_sizes, int n_in,
                              void* d_out, int out_size, void* d_ws, size_t ws_size,
                              hipStream_t stream) {
  (void)in_sizes; (void)n_in; (void)out_size; (void)ws_size;
  const float* tokens = (const float*)d_in[0];
  const float* cam_w1 = (const float*)d_in[2];
  const float* cam_b1 = (const float*)d_in[3];
  const float* cam_w2 = (const float*)d_in[4];
  const float* cam_b2 = (const float*)d_in[5];
  const float* cam_p  = (const float*)d_in[6];
  const float* cam_w3 = (const float*)d_in[7];
  const float* cam_b3 = (const float*)d_in[8];
  const float* cam_w4 = (const float*)d_in[9];
  const float* cam_b4 = (const float*)d_in[10];
  const float* reg_w1 = (const float*)d_in[11];
  const float* reg_b1 = (const float*)d_in[12];
  const float* reg_w2 = (const float*)d_in[13];
  const float* reg_b2 = (const float*)d_in[14];
  const float* reg_p  = (const float*)d_in[15];
  const float* reg_w3 = (const float*)d_in[16];
  const float* reg_b3 = (const float*)d_in[17];
  const float* reg_w4 = (const float*)d_in[18];
  const float* reg_b4 = (const float*)d_in[19];
  const float* pf_w1  = (const float*)d_in[20];
  const float* pf_b1  = (const float*)d_in[21];
  const float* pf_w2  = (const float*)d_in[22];
  const float* pf_b2  = (const float*)d_in[23];
  const float* ps_w1  = (const float*)d_in[24];
  const float* ps_b1  = (const float*)d_in[25];
  const float* ps_w2  = (const float*)d_in[26];
  const float* ps_b2  = (const float*)d_in[27];
  const float* dust   = (const float*)d_in[28];
  float* out = (float*)d_out;
  char* ws = (char*)d_ws;

  u16* Abf = (u16*)(ws + OFF_ABF);
  float* Sc = (float*)(ws + OFF_SC);
  float* ub = (float*)(ws + OFF_U);
  float* vb = (float*)(ws + OFF_V);
  float* pooled = (float*)(ws + OFF_POOL);
  float* hp = (float*)(ws + OFF_HP);
  u16* H   = (u16*)(ws + OFF_H);
  float* partial = (float*)(ws + OFF_PART);
  float* cp1 = (float*)(ws + OFF_CP1);
  float* gsb = (float*)(ws + OFF_GSB);
  float* o1b = (float*)(ws + OFF_O1B);
  float* cp2 = (float*)(ws + OFF_CP2);
  u16* Bt1cr = (u16*)(ws + OFF_BT1CR);
  u16* Bt2cr = (u16*)(ws + OFF_BT2CR);
  u16* Acr = (u16*)(ws + OFF_ACR);
  u16* A2  = (u16*)(ws + OFF_A2);
  float* FS = (float*)(ws + OFF_FS);
  u16* W1t = (u16*)(ws + OFF_W1T);
  u16* W2t = (u16*)(ws + OFF_W2T);
  float* b1c = (float*)(ws + OFF_B1C);
  float* b2c = (float*)(ws + OFF_B2C);

  hipMemsetAsync(vb, 0, (size_t)B_ * NPB * sizeof(float), stream);

  // ---- patch prep (convert + packs merged) + GEMMs ----
  k_prep_patch<<<18692, 256, 0, stream>>>(tokens, Abf, pf_w1, ps_w1, pf_w2, ps_w2,
                                          pf_b1, ps_b1, pf_b2, ps_b2,
                                          W1t, W2t, b1c, b2c);
  k_gemm<1, 1, 0><<<dim3(128, 8), 256, 0, stream>>>(Abf, W1t, b1c, (void*)H,
                                                    MROWS, N1, CDIM, nullptr);
  k_gemm<0, 0, 1><<<dim3(128, 2), 256, 0, stream>>>(H, W2t, b2c, (void*)FS,
                                                    MROWS, N2, N1, Sc);

  // ---- cam/reg path (Abf and H regions now dead) ----
  k_pack_cr<<<5248, 256, 0, stream>>>(cam_w1, reg_w1, cam_w2, reg_w2, tokens,
                                      Bt1cr, Bt2cr, Acr);
  k_gemm_splitk<<<dim3(1, 16, 8), 256, 0, stream>>>(Acr, Bt1cr, cp1, 2048, CDIM, 256);
  k_cr_fin1<<<dim3(128, 4), 256, 0, stream>>>(cp1, cam_b1, reg_b1, A2);
  k_gemm_splitk<<<dim3(1, 8, 8), 256, 0, stream>>>(A2, Bt2cr, cp2, 1024, N1, 128);
  k_cr_fin2<<<80, 512, 0, stream>>>(cp2, cam_b2, reg_b2, cam_p, reg_p, hp);
  k_cr3a<<<8, 512, 0, stream>>>(hp, cam_p, reg_p, gsb);
  k_cr3b<<<dim3(8, 4), 512, 0, stream>>>(gsb, cam_w3, reg_w3, cam_b3, reg_b3, o1b);
  k_cr3c<<<8, 512, 0, stream>>>(o1b, cam_w4, reg_w4, cam_b4, reg_b4, out);

  // ---- sinkhorn (dust row virtual) + pooled + outputs ----
  for (int it = 0; it < 3; ++it) {
    k_sink_u<<<B_ * MA, 256, 0, stream>>>(Sc, vb, ub, dust);
    k_sink_v<<<B_ * 16, 256, 0, stream>>>(Sc, ub, vb, dust);
  }
  k_pooled1<<<B_ * 64, 256, 0, stream>>>(FS, Sc, ub, vb, partial);
  k_pooled2<<<128, 256, 0, stream>>>(partial, pooled);
  k_patch_out<<<B_ * MD, 64, 0, stream>>>(pooled, out);
}

// Round 19
// 232.302 us; speedup vs baseline: 1.1590x; 1.0252x over previous
//
#include <hip/hip_runtime.h>

typedef unsigned short u16;
typedef unsigned int u32;

#define B_ 4
#define S_ 4
#define NTOK 1029
#define CDIM 2048
#define PSI 5
#define NPB 4096
#define MROWS 16384
#define N1 1024
#define N2 256
#define MD 64
#define MA 65

using bf16x8 = __attribute__((ext_vector_type(8))) short;
using f32x4  = __attribute__((ext_vector_type(4))) float;
using u16x8  = __attribute__((ext_vector_type(8))) unsigned short;

typedef __attribute__((address_space(1))) const void global_cvoid;
typedef __attribute__((address_space(3))) void lds_void;

__device__ __forceinline__ u16 f2b(float f) {
  u32 u = __builtin_bit_cast(u32, f);
  u32 r = (u + 0x7fffu + ((u >> 16) & 1u)) >> 16;
  return (u16)r;
}

// ---------------- merged prep: patch convert (fp32->bf16) + W1t/W2t/bias packs -------
__global__ void k_prep_patch(const float* __restrict__ tokens, u16* __restrict__ Abf,
                             const float* __restrict__ pfw1, const float* __restrict__ psw1,
                             const float* __restrict__ pfw2, const float* __restrict__ psw2,
                             const float* __restrict__ pfb1, const float* __restrict__ psb1,
                             const float* __restrict__ pfb2, const float* __restrict__ psb2,
                             u16* __restrict__ W1t, u16* __restrict__ W2t,
                             float* __restrict__ b1c, float* __restrict__ b2c) {
  __shared__ float tile[32][33];
  int id = blockIdx.x, tid = threadIdx.x;
  if (id < 16384) {
    size_t idx = (size_t)id * 256 + tid;
    size_t r = idx >> 8;
    int cv = (int)(idx & 255) << 3;
    int b = (int)(r >> 12), s = (int)((r >> 10) & 3), j = (int)(r & 1023);
    const float* src = tokens + ((size_t)((b * S_ + s) * NTOK + PSI + j)) * CDIM + cv;
    float4 v0 = *(const float4*)src;
    float4 v1 = *(const float4*)(src + 4);
    u16x8 o;
    o[0] = f2b(v0.x); o[1] = f2b(v0.y); o[2] = f2b(v0.z); o[3] = f2b(v0.w);
    o[4] = f2b(v1.x); o[5] = f2b(v1.y); o[6] = f2b(v1.z); o[7] = f2b(v1.w);
    *(u16x8*)(Abf + r * CDIM + cv) = o;
    return;
  }
  int id2 = id - 16384;
  int tx = tid & 31, ty = tid >> 5;
  if (id2 < 2048) {
    int kb = (id2 & 63) * 32, nb = (id2 >> 6) * 32;
    #pragma unroll
    for (int i = 0; i < 4; ++i) {
      int k = kb + ty + i * 8, n = nb + tx;
      tile[ty + i * 8][tx] = (n < 512) ? pfw1[(size_t)k * 512 + n] : psw1[(size_t)k * 512 + (n - 512)];
    }
    __syncthreads();
    #pragma unroll
    for (int i = 0; i < 4; ++i) {
      int n = nb + ty + i * 8, k = kb + tx;
      W1t[(size_t)n * CDIM + k] = f2b(tile[tx][ty + i * 8]);
    }
  } else if (id2 < 2304) {
    int i2 = id2 - 2048;
    int kb = (i2 & 31) * 32, jb = (i2 >> 5) * 32;
    #pragma unroll
    for (int i = 0; i < 4; ++i) {
      int k = kb + ty + i * 8, j = jb + tx;
      float v = 0.f;
      if (j < 128) { if (k < 512) v = pfw2[(size_t)k * 128 + j]; }
      else if (j < 192) { if (k >= 512) v = psw2[(size_t)(k - 512) * 64 + (j - 128)]; }
      tile[ty + i * 8][tx] = v;
    }
    __syncthreads();
    #pragma unroll
    for (int i = 0; i < 4; ++i) {
      int j = jb + ty + i * 8, k = kb + tx;
      W2t[(size_t)j * N1 + k] = f2b(tile[tx][ty + i * 8]);
    }
  } else {
    int t = (id2 - 2304) * 256 + tid;
    if (t < 1024) b1c[t] = (t < 512) ? pfb1[t] : psb1[t - 512];
    if (t < 256)  b2c[t] = (t < 128) ? pfb2[t] : ((t < 192) ? psb2[t - 128] : 0.f);
  }
}

// ---------------- merged cr-side packs: Bt1cr, Bt2cr, Acr ----------------
__global__ void k_pack_cr(const float* __restrict__ camw1, const float* __restrict__ regw1,
                          const float* __restrict__ camw2, const float* __restrict__ regw2,
                          const float* __restrict__ tokens,
                          u16* __restrict__ Bt1cr, u16* __restrict__ Bt2cr,
                          u16* __restrict__ Acr) {
  __shared__ float tile[32][33];
  int id = blockIdx.x, tid = threadIdx.x;
  int tx = tid & 31, ty = tid >> 5;
  if (id < 4096) {
    const float* src = (id < 2048) ? camw1 : regw1;
    u16* dst = Bt1cr + ((id < 2048) ? 0 : (size_t)1024 * CDIM);
    int i2 = id & 2047;
    int kb = (i2 & 63) * 32, nb = (i2 >> 6) * 32;
    #pragma unroll
    for (int i = 0; i < 4; ++i)
      tile[ty + i * 8][tx] = src[(size_t)(kb + ty + i * 8) * 1024 + nb + tx];
    __syncthreads();
    #pragma unroll
    for (int i = 0; i < 4; ++i)
      dst[(size_t)(nb + ty + i * 8) * CDIM + kb + tx] = f2b(tile[tx][ty + i * 8]);
  } else if (id < 5120) {
    int i3 = id - 4096;
    const float* src = (i3 < 512) ? camw2 : regw2;
    u16* dst = Bt2cr + ((i3 < 512) ? 0 : (size_t)512 * N1);
    int i2 = i3 & 511;
    int kb = (i2 & 31) * 32, nb = (i2 >> 5) * 32;
    #pragma unroll
    for (int i = 0; i < 4; ++i)
      tile[ty + i * 8][tx] = src[(size_t)(kb + ty + i * 8) * 512 + nb + tx];
    __syncthreads();
    #pragma unroll
    for (int i = 0; i < 4; ++i)
      dst[(size_t)(nb + ty + i * 8) * N1 + kb + tx] = f2b(tile[tx][ty + i * 8]);
  } else {
    int r = id - 5120;
    int c0 = tid << 3;
    u16x8 o;
    if (r >= 80) {
      #pragma unroll
      for (int i = 0; i < 8; ++i) o[i] = 0;
    } else {
      const float* src;
      if (r < 16) { int b = r >> 2, s = r & 3; src = tokens + ((size_t)(b * S_ + s) * NTOK) * CDIM; }
      else { int r2 = r - 16; int b = r2 >> 4, q = r2 & 15, s = q >> 2, t = (q & 3) + 1;
             src = tokens + ((size_t)(b * S_ + s) * NTOK + t) * CDIM; }
      float4 v0 = *(const float4*)(src + c0);
      float4 v1 = *(const float4*)(src + c0 + 4);
      o[0] = f2b(v0.x); o[1] = f2b(v0.y); o[2] = f2b(v0.z); o[3] = f2b(v0.w);
      o[4] = f2b(v1.x); o[5] = f2b(v1.y); o[6] = f2b(v1.z); o[7] = f2b(v1.w);
    }
    *(u16x8*)(Acr + (size_t)r * CDIM + c0) = o;
  }
}

// ---------------- bf16 MFMA GEMM: 2-buf, counted vmcnt(8), raw barriers, T2 swizzle --
#define STAGE_TILE(buf, k0)                                                    \
  {                                                                            \
    _Pragma("unroll")                                                          \
    for (int r = 0; r < 4; ++r) {                                              \
      __builtin_amdgcn_global_load_lds(                                        \
          (global_cvoid*)(A + abase + (size_t)(r * 32) * K + (k0)),            \
          (lds_void*)(&As[buf][lofs + r * 2048]), 16, 0, 0);                   \
      __builtin_amdgcn_global_load_lds(                                        \
          (global_cvoid*)(Bt + bbase + (size_t)(r * 32) * K + (k0)),           \
          (lds_void*)(&Bs[buf][lofs + r * 2048]), 16, 0, 0);                   \
    }                                                                          \
  }

#define COMPUTE_TILE(buf)                                                      \
  {                                                                            \
    _Pragma("unroll")                                                          \
    for (int kk = 0; kk < 64; kk += 32) {                                      \
      const int csw = (kk + hi8) ^ ((lane & 7) << 3);                          \
      bf16x8 af[4], bfr[4];                                                    \
      _Pragma("unroll")                                                        \
      for (int i = 0; i < 4; ++i) {                                            \
        af[i]  = *(const bf16x8*)&As[buf][((wr << 6) + (i << 4) + (lane & 15)) * 64 + csw]; \
        bfr[i] = *(const bf16x8*)&Bs[buf][((wc << 6) + (i << 4) + (lane & 15)) * 64 + csw]; \
      }                                                                        \
      _Pragma("unroll")                                                        \
      for (int mi = 0; mi < 4; ++mi)                                           \
        _Pragma("unroll")                                                      \
        for (int ni = 0; ni < 4; ++ni)                                         \
          acc[mi][ni] = __builtin_amdgcn_mfma_f32_16x16x32_bf16(af[mi], bfr[ni], acc[mi][ni], 0, 0, 0); \
    }                                                                          \
  }

template <int RELU, int OUTBF, int WRSC>
__global__ __launch_bounds__(256, 2)
void k_gemm(const u16* __restrict__ A, const u16* __restrict__ Bt,
            const float* __restrict__ bias, void* __restrict__ Cout,
            int M, int N, int K, float* __restrict__ ScOut) {
  __shared__ u16 As[2][128 * 64];
  __shared__ u16 Bs[2][128 * 64];
  const int tid = threadIdx.x;
  const int lane = tid & 63;
  const int wave = tid >> 6;
  const int tM = blockIdx.x << 7;
  const int tN = blockIdx.y << 7;
  const int wr = wave >> 1, wc = wave & 1;
  const int hi8 = (lane >> 4) << 3;

  const int srow = (wave << 3) + (lane >> 3);
  const int scolsw = ((lane & 7) ^ (lane >> 3)) << 3;
  const size_t abase = (size_t)(tM + srow) * K + scolsw;
  const size_t bbase = (size_t)(tN + srow) * K + scolsw;
  const int lofs = (wave << 9) + (lane << 3);

  f32x4 acc[4][4];
  #pragma unroll
  for (int i = 0; i < 4; ++i)
    #pragma unroll
    for (int j = 0; j < 4; ++j)
      acc[i][j] = (f32x4){0.f, 0.f, 0.f, 0.f};

  const int nt = K >> 6;
  STAGE_TILE(0, 0)
  STAGE_TILE(1, 64)
  for (int t = 0; t < nt; t += 2) {
    asm volatile("s_waitcnt vmcnt(8)" ::: "memory");
    __builtin_amdgcn_s_barrier();
    COMPUTE_TILE(0)
    __builtin_amdgcn_s_barrier();
    if (t + 2 < nt) STAGE_TILE(0, (t + 2) << 6)
    if (t + 1 == nt - 1) {
      asm volatile("s_waitcnt vmcnt(0)" ::: "memory");
    } else {
      asm volatile("s_waitcnt vmcnt(8)" ::: "memory");
    }
    __builtin_amdgcn_s_barrier();
    COMPUTE_TILE(1)
    __builtin_amdgcn_s_barrier();
    if (t + 3 < nt) STAGE_TILE(1, (t + 3) << 6)
  }

  #pragma unroll
  for (int ni = 0; ni < 4; ++ni) {
    const int col = tN + (wc << 6) + (ni << 4) + (lane & 15);
    const float bv = bias[col];
    #pragma unroll
    for (int mi = 0; mi < 4; ++mi) {
      #pragma unroll
      for (int j = 0; j < 4; ++j) {
        const int row = tM + (wr << 6) + (mi << 4) + ((lane >> 4) << 2) + j;
        float vv = acc[mi][ni][j] + bv;
        if (RELU) vv = fmaxf(vv, 0.f);
        if (OUTBF) ((u16*)Cout)[(size_t)row * N + col] = f2b(vv);
        else       ((float*)Cout)[(size_t)row * N + col] = vv;
        if (WRSC) {
          if (col >= 128 && col < 192)
            ScOut[((size_t)((row >> 12) * MD + (col - 128))) * NPB + (row & 4095)] = vv;
        }
      }
    }
  }
}

// ---------------- split-K MFMA GEMM, M=128 fixed (single-buffer, known-good) ----
__global__ __launch_bounds__(256, 2)
void k_gemm_splitk(const u16* __restrict__ A, const u16* __restrict__ Bt,
                   float* __restrict__ part, int N, int K, int KC) {
  __shared__ u16 As1[128 * 64];
  __shared__ u16 Bs1[128 * 64];
  const int tid = threadIdx.x;
  const int lane = tid & 63;
  const int wave = tid >> 6;
  const int tN = blockIdx.y << 7;
  const int kb = blockIdx.z * KC;
  const int wr = wave >> 1, wc = wave & 1;
  const int srow = (wave << 3) + (lane >> 3);
  const int scol = (lane & 7) << 3;
  const size_t abase = (size_t)srow * K + scol;
  const size_t bbase = (size_t)(tN + srow) * K + scol;
  u16* asw = &As1[(wave << 9) + (lane << 3)];
  u16* bsw = &Bs1[(wave << 9) + (lane << 3)];

  f32x4 acc[4][4];
  #pragma unroll
  for (int i = 0; i < 4; ++i)
    #pragma unroll
    for (int j = 0; j < 4; ++j)
      acc[i][j] = (f32x4){0.f, 0.f, 0.f, 0.f};

  for (int k0 = kb; k0 < kb + KC; k0 += 64) {
    #pragma unroll
    for (int r = 0; r < 4; ++r) {
      __builtin_amdgcn_global_load_lds(
          (global_cvoid*)(A + abase + (size_t)(r * 32) * K + k0),
          (lds_void*)(asw + r * 2048), 16, 0, 0);
      __builtin_amdgcn_global_load_lds(
          (global_cvoid*)(Bt + bbase + (size_t)(r * 32) * K + k0),
          (lds_void*)(bsw + r * 2048), 16, 0, 0);
    }
    __syncthreads();
    #pragma unroll
    for (int kk = 0; kk < 64; kk += 32) {
      bf16x8 af[4], bfr[4];
      #pragma unroll
      for (int i = 0; i < 4; ++i) {
        af[i]  = *(const bf16x8*)&As1[((wr << 6) + (i << 4) + (lane & 15)) * 64 + kk + ((lane >> 4) << 3)];
        bfr[i] = *(const bf16x8*)&Bs1[((wc << 6) + (i << 4) + (lane & 15)) * 64 + kk + ((lane >> 4) << 3)];
      }
      #pragma unroll
      for (int mi = 0; mi < 4; ++mi)
        #pragma unroll
        for (int ni = 0; ni < 4; ++ni)
          acc[mi][ni] = __builtin_amdgcn_mfma_f32_16x16x32_bf16(af[mi], bfr[ni], acc[mi][ni], 0, 0, 0);
    }
    __syncthreads();
  }

  float* dst = part + (size_t)blockIdx.z * 128 * N;
  #pragma unroll
  for (int ni = 0; ni < 4; ++ni) {
    const int col = tN + (wc << 6) + (ni << 4) + (lane & 15);
    #pragma unroll
    for (int mi = 0; mi < 4; ++mi) {
      #pragma unroll
      for (int j = 0; j < 4; ++j) {
        const int row = (wr << 6) + (mi << 4) + ((lane >> 4) << 2) + j;
        dst[(size_t)row * N + col] = acc[mi][ni][j];
      }
    }
  }
}

// ---------------- cr fin1: reduce part1(kc=8) + bias + relu -> A2 bf16 [128][1024] ----
__global__ void k_cr_fin1(const float* __restrict__ part1,
                          const float* __restrict__ camb1, const float* __restrict__ regb1,
                          u16* __restrict__ A2) {
  int r = blockIdx.x;
  int j = blockIdx.y * 256 + threadIdx.x;
  if (r >= 80) { A2[(size_t)r * N1 + j] = 0; return; }
  bool cam = (r < 16);
  int cm = j + (cam ? 0 : 1024);
  float s = 0.f;
  #pragma unroll
  for (int kc = 0; kc < 8; ++kc) s += part1[((size_t)kc * 128 + r) * 2048 + cm];
  s += cam ? camb1[j] : regb1[j];
  A2[(size_t)r * N1 + j] = f2b(fmaxf(s, 0.f));
}

// ---------------- cr fin2: reduce part2(kc=8) + bias + l2norm + clip^p -> hp[80][512] -
__global__ __launch_bounds__(512)
void k_cr_fin2(const float* __restrict__ part2,
               const float* __restrict__ camb2, const float* __restrict__ regb2,
               const float* __restrict__ camp, const float* __restrict__ regp,
               float* __restrict__ hp) {
  __shared__ float red[8];
  int r = blockIdx.x;
  int j = threadIdx.x;
  bool cam = (r < 16);
  int cm = j + (cam ? 0 : 512);
  float s = 0.f;
  #pragma unroll
  for (int kc = 0; kc < 8; ++kc) s += part2[((size_t)kc * 128 + r) * 1024 + cm];
  s += cam ? camb2[j] : regb2[j];
  float ss = s * s;
  #pragma unroll
  for (int o = 32; o; o >>= 1) ss += __shfl_down(ss, o);
  if ((j & 63) == 0) red[j >> 6] = ss;
  __syncthreads();
  float tot = 0.f;
  #pragma unroll
  for (int i = 0; i < 8; ++i) tot += red[i];
  float inv = 1.f / fmaxf(sqrtf(tot), 1e-12f);
  float t = fmaxf(s * inv, 1e-6f);
  hp[(size_t)r * 512 + j] = powf(t, cam ? camp[0] : regp[0]);
}

// ---------------- cr3a: GeM finalize -> gsb[8][512] ----------------
__global__ __launch_bounds__(512)
void k_cr3a(const float* __restrict__ hp, const float* __restrict__ camp,
            const float* __restrict__ regp, float* __restrict__ gsb) {
  int pb = blockIdx.x;
  bool cam = (pb < 4);
  int b = pb & 3;
  float p = cam ? camp[0] : regp[0];
  int L = cam ? 4 : 16;
  int row0 = cam ? b * 4 : 16 + b * 16;
  int o = threadIdx.x;
  float s = 0.f;
  for (int r = 0; r < L; ++r) s += hp[(size_t)(row0 + r) * 512 + o];
  gsb[pb * 512 + o] = powf(s / (float)L, 1.f / p);
}

// ---------------- cr3b: o1[8][512] = ReLU(gs @ W3 + b3), k-split x4 ----------------
__global__ __launch_bounds__(512)
void k_cr3b(const float* __restrict__ gsb,
            const float* __restrict__ camw3, const float* __restrict__ regw3,
            const float* __restrict__ camb3, const float* __restrict__ regb3,
            float* __restrict__ o1b) {
  __shared__ float gls[512];
  __shared__ float part[4][128];
  int pb = blockIdx.x, och = blockIdx.y;
  bool cam = (pb < 4);
  const float* W3 = cam ? camw3 : regw3;
  const float* B3 = cam ? camb3 : regb3;
  int tid = threadIdx.x;
  gls[tid] = gsb[pb * 512 + tid];
  __syncthreads();
  int col = tid & 127, kq = tid >> 7;
  int o = (och << 7) + col;
  float acc = 0.f;
  const float* w = W3 + (size_t)(kq << 7) * 512 + o;
  #pragma unroll 8
  for (int kk = 0; kk < 128; ++kk) acc += gls[(kq << 7) + kk] * w[(size_t)kk * 512];
  part[kq][col] = acc;
  __syncthreads();
  if (kq == 0) {
    float s = part[0][col] + part[1][col] + part[2][col] + part[3][col] + B3[o];
    o1b[pb * 512 + o] = fmaxf(s, 0.f);
  }
}

// ---------------- cr3c: out = l2norm(o1 @ W4 + b4), k-split x2 + block l2norm -------
__global__ __launch_bounds__(512)
void k_cr3c(const float* __restrict__ o1b,
            const float* __restrict__ camw4, const float* __restrict__ regw4,
            const float* __restrict__ camb4, const float* __restrict__ regb4,
            float* __restrict__ out) {
  __shared__ float o1s[512];
  __shared__ float part[2][256];
  __shared__ float vsq[256];
  __shared__ float red[4];
  int pb = blockIdx.x;
  bool cam = (pb < 4);
  int path = pb >> 2, b = pb & 3;
  const float* W4 = cam ? camw4 : regw4;
  const float* B4 = cam ? camb4 : regb4;
  int tid = threadIdx.x;
  o1s[tid] = o1b[pb * 512 + tid];
  __syncthreads();
  int col = tid & 255, kh = tid >> 8;
  float acc = 0.f;
  const float* w = W4 + (size_t)(kh << 8) * 256 + col;
  #pragma unroll 8
  for (int kk = 0; kk < 256; ++kk) acc += o1s[(kh << 8) + kk] * w[(size_t)kk * 256];
  part[kh][col] = acc;
  __syncthreads();
  float val = 0.f;
  if (kh == 0) {
    val = part[0][col] + part[1][col] + B4[col];
    vsq[col] = val * val;
  }
  __syncthreads();
  float ss = (tid < 256) ? vsq[tid] : 0.f;
  #pragma unroll
  for (int o = 32; o; o >>= 1) ss += __shfl_down(ss, o);
  if (tid < 256 && (tid & 63) == 0) red[tid >> 6] = ss;
  __syncthreads();
  if (kh == 0) {
    float tot = red[0] + red[1] + red[2] + red[3];
    float inv = 1.f / fmaxf(sqrtf(tot), 1e-12f);
    out[(size_t)b * 8704 + 8192 + path * 256 + col] = val * inv;
  }
}

// ---------------- sinkhorn: u update — online LSE; dust row k==64 is virtual ---------
// FIRST=1: iteration 0, v==0 everywhere -> skip v reads entirely (also removes the
// need to memset vb; workspace poison never read).
template <int FIRST>
__global__ void k_sink_u(const float* __restrict__ Sc, const float* __restrict__ v,
                         float* __restrict__ u, const float* __restrict__ dust) {
  __shared__ float redm[4], reds[4];
  int b = blockIdx.x / MA, k = blockIdx.x % MA;
  const float* vb = v + (size_t)b * NPB;
  int tid = threadIdx.x;
  float mx = -1e30f, s = 0.f;
  if (k < MD) {
    const float* row = Sc + ((size_t)(b * MD) + k) * NPB;
    for (int n = tid; n < NPB; n += 256) {
      float x = FIRST ? row[n] : (row[n] + vb[n]);
      float m2 = fmaxf(mx, x);
      s = s * __expf(mx - m2) + __expf(x - m2);
      mx = m2;
    }
  } else {
    float d0 = dust[0];
    for (int n = tid; n < NPB; n += 256) {
      float x = FIRST ? d0 : (d0 + vb[n]);
      float m2 = fmaxf(mx, x);
      s = s * __expf(mx - m2) + __expf(x - m2);
      mx = m2;
    }
  }
  #pragma unroll
  for (int o = 32; o; o >>= 1) {
    float mo = __shfl_down(mx, o), so = __shfl_down(s, o);
    float m2 = fmaxf(mx, mo);
    s = s * __expf(mx - m2) + so * __expf(mo - m2);
    mx = m2;
  }
  if ((tid & 63) == 0) { redm[tid >> 6] = mx; reds[tid >> 6] = s; }
  __syncthreads();
  if (tid == 0) {
    float M = redm[0];
    #pragma unroll
    for (int i = 1; i < 4; ++i) M = fmaxf(M, redm[i]);
    float S = 0.f;
    #pragma unroll
    for (int i = 0; i < 4; ++i) S += reds[i] * __expf(redm[i] - M);
    const float nrm = -logf((float)(NPB + MD));
    float la = (k == MD) ? (nrm + logf((float)(NPB - MD))) : nrm;
    u[b * MA + k] = la - (M + __logf(S));
  }
}

// ---------------- sinkhorn: v update (col LSE over 64 Sc rows + virtual dust) --------
__global__ void k_sink_v(const float* __restrict__ Sc, const float* __restrict__ u,
                         float* __restrict__ v, const float* __restrict__ dust) {
  __shared__ float us[MA];
  int b = blockIdx.x >> 4;
  int n = ((blockIdx.x & 15) << 8) + threadIdx.x;
  if (threadIdx.x < MA) us[threadIdx.x] = u[b * MA + threadIdx.x];
  __syncthreads();
  const float* Sb = Sc + (size_t)b * MD * NPB + n;
  float d0 = dust[0];
  float mx = d0 + us[MD];
  for (int k = 0; k < MD; ++k) mx = fmaxf(mx, Sb[(size_t)k * NPB] + us[k]);
  float s = __expf(d0 + us[MD] - mx);
  for (int k = 0; k < MD; ++k) s += __expf(Sb[(size_t)k * NPB] + us[k] - mx);
  const float nrm = -logf((float)(NPB + MD));
  v[(size_t)b * NPB + n] = nrm - (mx + __logf(s));
}

// ---------------- pooled stage 1 (P fused): partial[b][j][c][k] over 64-n chunks ------
__global__ __launch_bounds__(256)
void k_pooled1(const float* __restrict__ FS, const float* __restrict__ Sc,
               const float* __restrict__ u, const float* __restrict__ v,
               float* __restrict__ partial) {
  __shared__ float Fs[64][132];
  __shared__ float Ps[64][68];
  int b = blockIdx.x >> 6, j = blockIdx.x & 63;
  int n0 = j << 6;
  int tid = threadIdx.x;
  {
    int r = tid >> 5;
    int c4 = (tid & 31) << 2;
    #pragma unroll
    for (int i = 0; i < 8; ++i) {
      int n = r + (i << 3);
      float4 vv = *(const float4*)&FS[((size_t)(b * NPB + n0 + n)) * N2 + c4];
      *(float4*)&Fs[n][c4] = vv;
    }
  }
  {
    const float nrm = -logf((float)(NPB + MD));
    int r = tid >> 4;
    int c4 = (tid & 15) << 2;
    #pragma unroll
    for (int i = 0; i < 4; ++i) {
      int k = r + (i << 4);
      float uk = u[b * MA + k];
      float4 sv = *(const float4*)&Sc[((size_t)(b * MD) + k) * NPB + n0 + c4];
      float4 vv = *(const float4*)&v[(size_t)b * NPB + n0 + c4];
      float4 o;
      o.x = __expf(sv.x + uk + vv.x - nrm);
      o.y = __expf(sv.y + uk + vv.y - nrm);
      o.z = __expf(sv.z + uk + vv.z - nrm);
      o.w = __expf(sv.w + uk + vv.w - nrm);
      *(float4*)&Ps[k][c4] = o;
    }
  }
  __syncthreads();
  int tc = tid & 31, tk = tid >> 5;
  int c0 = tc << 2, k0 = tk << 3;
  float acc[4][8];
  #pragma unroll
  for (int i = 0; i < 4; ++i)
    #pragma unroll
    for (int kk = 0; kk < 8; ++kk) acc[i][kk] = 0.f;
  for (int n = 0; n < 64; ++n) {
    float4 f = *(const float4*)&Fs[n][c0];
    float pv[8];
    #pragma unroll
    for (int kk = 0; kk < 8; ++kk) pv[kk] = Ps[k0 + kk][n];
    #pragma unroll
    for (int i = 0; i < 4; ++i) {
      float fv = ((const float*)&f)[i];
      #pragma unroll
      for (int kk = 0; kk < 8; ++kk) acc[i][kk] += fv * pv[kk];
    }
  }
  float* dst = partial + ((size_t)(b * 64 + j) << 13);
  #pragma unroll
  for (int i = 0; i < 4; ++i) {
    float4 lo = {acc[i][0], acc[i][1], acc[i][2], acc[i][3]};
    float4 hi = {acc[i][4], acc[i][5], acc[i][6], acc[i][7]};
    *(float4*)&dst[((c0 + i) << 6) + k0] = lo;
    *(float4*)&dst[((c0 + i) << 6) + k0 + 4] = hi;
  }
}

// ---------------- pooled stage 2: reduce 64 partials, coalesced ----------------
__global__ void k_pooled2(const float* __restrict__ partial, float* __restrict__ pooled) {
  int o = blockIdx.x * 256 + threadIdx.x;
  int b = o >> 13, rem = o & 8191;
  const float* src = partial + ((size_t)b << 19) + rem;
  float s = 0.f;
  #pragma unroll 8
  for (int j = 0; j < 64; ++j) s += src[(size_t)j << 13];
  pooled[o] = s;
}

// ---------------- patch output: l2norm over c (128), write [b][c*64+k] --------------
__global__ void k_patch_out(const float* __restrict__ pooled, float* __restrict__ out) {
  int b = blockIdx.x >> 6, k = blockIdx.x & 63;
  int tid = threadIdx.x;
  float v0 = pooled[((size_t)(b * 128) + tid) * MD + k];
  float v1 = pooled[((size_t)(b * 128) + 64 + tid) * MD + k];
  float ss = v0 * v0 + v1 * v1;
  #pragma unroll
  for (int o = 32; o; o >>= 1) ss += __shfl_down(ss, o);
  ss = __shfl(ss, 0);
  float inv = 1.f / fmaxf(sqrtf(ss), 1e-12f);
  out[(size_t)b * 8704 + tid * 64 + k] = v0 * inv;
  out[(size_t)b * 8704 + (64 + tid) * 64 + k] = v1 * inv;
}

// ---------------- workspace layout (bytes) ----------------
#define OFF_ABF 0u
#define OFF_SC 0u                         // B*64*4096*4 (compact, no dust row)
#define OFF_U 4259840u
#define OFF_V 4263936u
#define OFF_POOL 8523776u
#define OFF_HP 8982528u                   // written post-GEMM2 only!
#define OFF_H 67108864u
#define OFF_PART OFF_H
#define OFF_CP1 75497472u
#define OFF_GSB OFF_CP1
#define OFF_O1B 75513856u
#define OFF_CP2 83886080u
#define OFF_BT1CR 88080384u
#define OFF_BT2CR 96468992u
#define OFF_ACR 98566144u
#define OFF_A2 99090432u
#define OFF_FS 100663296u
#define OFF_W1T 117440512u
#define OFF_W2T 121634816u
#define OFF_B1C 122159104u
#define OFF_B2C 122163200u

extern "C" void kernel_launch(void* const* d_in, const int* in_sizes, int n_in,
                              void* d_out, int out_size, void* d_ws, size_t ws_size,
                              hipStream_t stream) {
  (void)in_sizes; (void)n_in; (void)out_size; (void)ws_size;
  const float* tokens = (const float*)d_in[0];
  const float* cam_w1 = (const float*)d_in[2];
  const float* cam_b1 = (const float*)d_in[3];
  const float* cam_w2 = (const float*)d_in[4];
  const float* cam_b2 = (const float*)d_in[5];
  const float* cam_p  = (const float*)d_in[6];
  const float* cam_w3 = (const float*)d_in[7];
  const float* cam_b3 = (const float*)d_in[8];
  const float* cam_w4 = (const float*)d_in[9];
  const float* cam_b4 = (const float*)d_in[10];
  const float* reg_w1 = (const float*)d_in[11];
  const float* reg_b1 = (const float*)d_in[12];
  const float* reg_w2 = (const float*)d_in[13];
  const float* reg_b2 = (const float*)d_in[14];
  const float* reg_p  = (const float*)d_in[15];
  const float* reg_w3 = (const float*)d_in[16];
  const float* reg_b3 = (const float*)d_in[17];
  const float* reg_w4 = (const float*)d_in[18];
  const float* reg_b4 = (const float*)d_in[19];
  const float* pf_w1  = (const float*)d_in[20];
  const float* pf_b1  = (const float*)d_in[21];
  const float* pf_w2  = (const float*)d_in[22];
  const float* pf_b2  = (const float*)d_in[23];
  const float* ps_w1  = (const float*)d_in[24];
  const float* ps_b1  = (const float*)d_in[25];
  const float* ps_w2  = (const float*)d_in[26];
  const float* ps_b2  = (const float*)d_in[27];
  const float* dust   = (const float*)d_in[28];
  float* out = (float*)d_out;
  char* ws = (char*)d_ws;

  u16* Abf = (u16*)(ws + OFF_ABF);
  float* Sc = (float*)(ws + OFF_SC);
  float* ub = (float*)(ws + OFF_U);
  float* vb = (float*)(ws + OFF_V);
  float* pooled = (float*)(ws + OFF_POOL);
  float* hp = (float*)(ws + OFF_HP);
  u16* H   = (u16*)(ws + OFF_H);
  float* partial = (float*)(ws + OFF_PART);
  float* cp1 = (float*)(ws + OFF_CP1);
  float* gsb = (float*)(ws + OFF_GSB);
  float* o1b = (float*)(ws + OFF_O1B);
  float* cp2 = (float*)(ws + OFF_CP2);
  u16* Bt1cr = (u16*)(ws + OFF_BT1CR);
  u16* Bt2cr = (u16*)(ws + OFF_BT2CR);
  u16* Acr = (u16*)(ws + OFF_ACR);
  u16* A2  = (u16*)(ws + OFF_A2);
  float* FS = (float*)(ws + OFF_FS);
  u16* W1t = (u16*)(ws + OFF_W1T);
  u16* W2t = (u16*)(ws + OFF_W2T);
  float* b1c = (float*)(ws + OFF_B1C);
  float* b2c = (float*)(ws + OFF_B2C);

  // ---- patch prep (convert + packs merged) + GEMMs ----
  k_prep_patch<<<18692, 256, 0, stream>>>(tokens, Abf, pf_w1, ps_w1, pf_w2, ps_w2,
                                          pf_b1, ps_b1, pf_b2, ps_b2,
                                          W1t, W2t, b1c, b2c);
  k_gemm<1, 1, 0><<<dim3(128, 8), 256, 0, stream>>>(Abf, W1t, b1c, (void*)H,
                                                    MROWS, N1, CDIM, nullptr);
  k_gemm<0, 0, 1><<<dim3(128, 2), 256, 0, stream>>>(H, W2t, b2c, (void*)FS,
                                                    MROWS, N2, N1, Sc);

  // ---- cam/reg path (Abf and H regions now dead) ----
  k_pack_cr<<<5248, 256, 0, stream>>>(cam_w1, reg_w1, cam_w2, reg_w2, tokens,
                                      Bt1cr, Bt2cr, Acr);
  k_gemm_splitk<<<dim3(1, 16, 8), 256, 0, stream>>>(Acr, Bt1cr, cp1, 2048, CDIM, 256);
  k_cr_fin1<<<dim3(128, 4), 256, 0, stream>>>(cp1, cam_b1, reg_b1, A2);
  k_gemm_splitk<<<dim3(1, 8, 8), 256, 0, stream>>>(A2, Bt2cr, cp2, 1024, N1, 128);
  k_cr_fin2<<<80, 512, 0, stream>>>(cp2, cam_b2, reg_b2, cam_p, reg_p, hp);
  k_cr3a<<<8, 512, 0, stream>>>(hp, cam_p, reg_p, gsb);
  k_cr3b<<<dim3(8, 4), 512, 0, stream>>>(gsb, cam_w3, reg_w3, cam_b3, reg_b3, o1b);
  k_cr3c<<<8, 512, 0, stream>>>(o1b, cam_w4, reg_w4, cam_b4, reg_b4, out);

  // ---- sinkhorn (dust row virtual; iter 0 skips v, so no memset needed) ----
  k_sink_u<1><<<B_ * MA, 256, 0, stream>>>(Sc, vb, ub, dust);
  k_sink_v<<<B_ * 16, 256, 0, stream>>>(Sc, ub, vb, dust);
  for (int it = 1; it < 3; ++it) {
    k_sink_u<0><<<B_ * MA, 256, 0, stream>>>(Sc, vb, ub, dust);
    k_sink_v<<<B_ * 16, 256, 0, stream>>>(Sc, ub, vb, dust);
  }
  k_pooled1<<<B_ * 64, 256, 0, stream>>>(FS, Sc, ub, vb, partial);
  k_pooled2<<<128, 256, 0, stream>>>(partial, pooled);
  k_patch_out<<<B_ * MD, 64, 0, stream>>>(pooled, out);
}